// Round 1
// baseline (829.290 us; speedup 1.0000x reference)
//
#include <hip/hip_runtime.h>
#include <math.h>

typedef __attribute__((ext_vector_type(4))) float f32x4;
typedef __attribute__((ext_vector_type(8))) short bf16x8;

#define MFMA16(a, b, c) __builtin_amdgcn_mfma_f32_16x16x32_bf16((a), (b), (c), 0, 0, 0)

__device__ __forceinline__ unsigned short f2bf(float f) {
    union { float f; unsigned u; } v; v.f = f;
    unsigned u = v.u;
    unsigned r = u + 0x7fffu + ((u >> 16) & 1u);
    return (unsigned short)(r >> 16);
}
__device__ __forceinline__ float bf2f(unsigned short h) {
    union { float f; unsigned u; } v; v.u = ((unsigned)h) << 16;
    return v.f;
}

// ---------------------------------------------------------------- prep X
__global__ __launch_bounds__(256) void prep_x_kernel(
    const float* __restrict__ X, unsigned short* __restrict__ XH,
    unsigned short* __restrict__ XL) {
    int i = (blockIdx.x * 256 + threadIdx.x) * 4;
    float4 v = *reinterpret_cast<const float4*>(X + i);
    ushort4 h, l;
    h.x = f2bf(v.x); l.x = f2bf(v.x - bf2f(h.x));
    h.y = f2bf(v.y); l.y = f2bf(v.y - bf2f(h.y));
    h.z = f2bf(v.z); l.z = f2bf(v.z - bf2f(h.z));
    h.w = f2bf(v.w); l.w = f2bf(v.w - bf2f(h.w));
    *reinterpret_cast<ushort4*>(XH + i) = h;
    *reinterpret_cast<ushort4*>(XL + i) = l;
}

// ---------------------------------------------------------------- prep W (transpose + hi/lo)
__global__ __launch_bounds__(256) void prep_w_kernel(
    const float* __restrict__ Wq, const float* __restrict__ Wk,
    const float* __restrict__ Wv, unsigned short* __restrict__ WTH,
    unsigned short* __restrict__ WTL) {
    __shared__ float T[64][65];
    int z = blockIdx.z;
    const float* W = (z == 0) ? Wq : ((z == 1) ? Wk : Wv);
    unsigned short* WH = WTH + (size_t)z * 1024 * 1024;
    unsigned short* WL = WTL + (size_t)z * 1024 * 1024;
    int k0 = blockIdx.x * 64, n0 = blockIdx.y * 64;
    int t = threadIdx.x;
    for (int i = 0; i < 4; i++) {
        int fid = t + i * 256;
        int rr = fid >> 4, cc = fid & 15;
        float4 v = *reinterpret_cast<const float4*>(W + (size_t)(k0 + rr) * 1024 + n0 + cc * 4);
        T[rr][cc * 4 + 0] = v.x; T[rr][cc * 4 + 1] = v.y;
        T[rr][cc * 4 + 2] = v.z; T[rr][cc * 4 + 3] = v.w;
    }
    __syncthreads();
    for (int i = 0; i < 4; i++) {
        int e = t + i * 256;
        int n = e >> 4, kq = (e & 15) * 4;
        ushort4 h, l;
        float a0 = T[kq + 0][n], a1 = T[kq + 1][n], a2 = T[kq + 2][n], a3 = T[kq + 3][n];
        h.x = f2bf(a0); l.x = f2bf(a0 - bf2f(h.x));
        h.y = f2bf(a1); l.y = f2bf(a1 - bf2f(h.y));
        h.z = f2bf(a2); l.z = f2bf(a2 - bf2f(h.z));
        h.w = f2bf(a3); l.w = f2bf(a3 - bf2f(h.w));
        size_t o = (size_t)(n0 + n) * 1024 + k0 + kq;
        *reinterpret_cast<ushort4*>(WH + o) = h;
        *reinterpret_cast<ushort4*>(WL + o) = l;
    }
}

// ---------------------------------------------------------------- QKV GEMM
// C[m][n] = X[m][:] . W[:][n] + bias ; hi/lo split (3 MFMAs per pair).
// z=0: Q (scaled 0.125, layout [b][h][s][d]); z=1: K; z=2: V transposed [b][h][d][s].
__global__ __launch_bounds__(256) void qkv_gemm_kernel(
    const unsigned short* __restrict__ XH, const unsigned short* __restrict__ XL,
    const unsigned short* __restrict__ WTH, const unsigned short* __restrict__ WTL,
    const float* __restrict__ bq, const float* __restrict__ bk,
    const float* __restrict__ bv,
    unsigned short* __restrict__ QH, unsigned short* __restrict__ QL,
    unsigned short* __restrict__ KH, unsigned short* __restrict__ KL,
    unsigned short* __restrict__ VTH, unsigned short* __restrict__ VTL) {
    int z = blockIdx.z;
    const unsigned short* WH = WTH + (size_t)z * 1024 * 1024;
    const unsigned short* WL = WTL + (size_t)z * 1024 * 1024;
    const float* bias = (z == 0) ? bq : ((z == 1) ? bk : bv);
    int m0 = blockIdx.x * 64, n0 = blockIdx.y * 64;
    int tid = threadIdx.x, lane = tid & 63, wid = tid >> 6;
    int wm = wid >> 1, wn = wid & 1;
    int g = lane >> 4, r16 = lane & 15;

    f32x4 acc[2][2] = {};
    int mrow[2], nrow[2];
    for (int mi = 0; mi < 2; mi++) mrow[mi] = m0 + wm * 32 + mi * 16 + r16;
    for (int ni = 0; ni < 2; ni++) nrow[ni] = n0 + wn * 32 + ni * 16 + r16;

    for (int k0 = 0; k0 < 1024; k0 += 32) {
        int ko = k0 + g * 8;
        bf16x8 ah[2], al[2], bh[2], bl[2];
        for (int mi = 0; mi < 2; mi++) {
            ah[mi] = *reinterpret_cast<const bf16x8*>(XH + (size_t)mrow[mi] * 1024 + ko);
            al[mi] = *reinterpret_cast<const bf16x8*>(XL + (size_t)mrow[mi] * 1024 + ko);
        }
        for (int ni = 0; ni < 2; ni++) {
            bh[ni] = *reinterpret_cast<const bf16x8*>(WH + (size_t)nrow[ni] * 1024 + ko);
            bl[ni] = *reinterpret_cast<const bf16x8*>(WL + (size_t)nrow[ni] * 1024 + ko);
        }
        for (int mi = 0; mi < 2; mi++)
            for (int ni = 0; ni < 2; ni++) {
                acc[mi][ni] = MFMA16(ah[mi], bh[ni], acc[mi][ni]);
                acc[mi][ni] = MFMA16(ah[mi], bl[ni], acc[mi][ni]);
                acc[mi][ni] = MFMA16(al[mi], bh[ni], acc[mi][ni]);
            }
    }
    // epilogue: D row = g*4+r (m), col = r16 (n)
    for (int mi = 0; mi < 2; mi++)
        for (int ni = 0; ni < 2; ni++)
            for (int r = 0; r < 4; r++) {
                int m = m0 + wm * 32 + mi * 16 + g * 4 + r;
                int n = n0 + wn * 32 + ni * 16 + r16;
                float val = acc[mi][ni][r] + bias[n];
                if (z == 0) val *= 0.125f;
                int b = m >> 11, s = m & 2047, hh = n >> 6, d = n & 63;
                unsigned short hi = f2bf(val);
                unsigned short lo = f2bf(val - bf2f(hi));
                if (z == 2) {
                    size_t o = ((size_t)(b * 16 + hh) * 64 + d) * 2048 + s;
                    VTH[o] = hi; VTL[o] = lo;
                } else {
                    size_t o = ((size_t)(b * 16 + hh) * 2048 + s) * 64 + d;
                    if (z == 0) { QH[o] = hi; QL[o] = lo; }
                    else        { KH[o] = hi; KL[o] = lo; }
                }
            }
}

// ---------------------------------------------------------------- attention
// grid (S/64, B*H); block 256 = 4 waves x 16 q-rows each. KBLK=32.
// Swapped QK^T: mfma(K, Q) -> D[k][q]: lane holds q = lane&15, k = sub*16 + g*4 + r.
__global__ __launch_bounds__(256) void attn_kernel(
    const unsigned short* __restrict__ QH, const unsigned short* __restrict__ QL,
    const unsigned short* __restrict__ KH, const unsigned short* __restrict__ KL,
    const unsigned short* __restrict__ VTH, const unsigned short* __restrict__ VTL,
    const int* __restrict__ mask, float* __restrict__ out) {
    __shared__ unsigned short P_lds[4][2][16][40];  // [wave][dbuf][q][k], pad 32->40
    int bh = blockIdx.y;
    int b = bh >> 4, h = bh & 15;
    int tid = threadIdx.x, lane = tid & 63, wid = tid >> 6;
    int g = lane >> 4, r16 = lane & 15;
    size_t qk_base = (size_t)bh * 2048 * 64;
    size_t vt_base = (size_t)bh * 64 * 2048;
    int q0 = blockIdx.x * 64 + wid * 16;

    // Q fragments (B-operand): lane holds q-row = r16, d-slice g*8
    bf16x8 qh[2], ql[2];
    for (int d = 0; d < 2; d++) {
        size_t o = qk_base + (size_t)(q0 + r16) * 64 + d * 32 + g * 8;
        qh[d] = *reinterpret_cast<const bf16x8*>(QH + o);
        ql[d] = *reinterpret_cast<const bf16x8*>(QL + o);
    }
    f32x4 ctx[4] = {};
    float m_st = -INFINITY, l_st = 0.f;
    const int* mrow = mask + b * 2048;

    for (int k0 = 0; k0 < 2048; k0 += 32) {
        // QK^T (swapped): A = K rows, B = Q rows
        f32x4 sc[2];
        for (int sub = 0; sub < 2; sub++) {
            f32x4 a = {};
            for (int d = 0; d < 2; d++) {
                size_t o = qk_base + (size_t)(k0 + sub * 16 + r16) * 64 + d * 32 + g * 8;
                bf16x8 kh = *reinterpret_cast<const bf16x8*>(KH + o);
                bf16x8 kl = *reinterpret_cast<const bf16x8*>(KL + o);
                a = MFMA16(kh, qh[d], a);
                a = MFMA16(kh, ql[d], a);
                a = MFMA16(kl, qh[d], a);
            }
            sc[sub] = a;
        }
        // key mask (ref: where(mask==0, -1e8))
        for (int sub = 0; sub < 2; sub++) {
            int4 mk = *reinterpret_cast<const int4*>(mrow + k0 + sub * 16 + g * 4);
            if (mk.x == 0) sc[sub][0] = -1e8f;
            if (mk.y == 0) sc[sub][1] = -1e8f;
            if (mk.z == 0) sc[sub][2] = -1e8f;
            if (mk.w == 0) sc[sub][3] = -1e8f;
        }
        // online softmax: row (q) reduce = per-lane 8 vals + xor16 + xor32
        float mc = fmaxf(fmaxf(fmaxf(sc[0][0], sc[0][1]), fmaxf(sc[0][2], sc[0][3])),
                         fmaxf(fmaxf(sc[1][0], sc[1][1]), fmaxf(sc[1][2], sc[1][3])));
        mc = fmaxf(mc, __shfl_xor(mc, 16));
        mc = fmaxf(mc, __shfl_xor(mc, 32));
        float m_new = fmaxf(m_st, mc);
        float fac = __expf(m_st - m_new);
        float psum = 0.f;
        ushort4 pw[2];
        {
            float p0, p1, p2, p3;
            p0 = __expf(sc[0][0] - m_new); p1 = __expf(sc[0][1] - m_new);
            p2 = __expf(sc[0][2] - m_new); p3 = __expf(sc[0][3] - m_new);
            pw[0].x = f2bf(p0); pw[0].y = f2bf(p1); pw[0].z = f2bf(p2); pw[0].w = f2bf(p3);
            psum += p0 + p1 + p2 + p3;
            p0 = __expf(sc[1][0] - m_new); p1 = __expf(sc[1][1] - m_new);
            p2 = __expf(sc[1][2] - m_new); p3 = __expf(sc[1][3] - m_new);
            pw[1].x = f2bf(p0); pw[1].y = f2bf(p1); pw[1].z = f2bf(p2); pw[1].w = f2bf(p3);
            psum += p0 + p1 + p2 + p3;
        }
        psum += __shfl_xor(psum, 16);
        psum += __shfl_xor(psum, 32);
        l_st = l_st * fac + psum;
        m_st = m_new;
        // redistribute rescale factor to ctx row layout (row = g*4+r)
        float fr0 = __shfl(fac, (lane & 48) | (g * 4 + 0));
        float fr1 = __shfl(fac, (lane & 48) | (g * 4 + 1));
        float fr2 = __shfl(fac, (lane & 48) | (g * 4 + 2));
        float fr3 = __shfl(fac, (lane & 48) | (g * 4 + 3));
        for (int ds = 0; ds < 4; ds++) {
            ctx[ds][0] *= fr0; ctx[ds][1] *= fr1;
            ctx[ds][2] *= fr2; ctx[ds][3] *= fr3;
        }
        // P -> LDS [q][k] (double-buffered), then read back as A-fragment
        int buf = (k0 >> 5) & 1;
        *reinterpret_cast<ushort4*>(&P_lds[wid][buf][r16][0 * 16 + g * 4]) = pw[0];
        *reinterpret_cast<ushort4*>(&P_lds[wid][buf][r16][1 * 16 + g * 4]) = pw[1];
        __syncthreads();
        bf16x8 pa = *reinterpret_cast<bf16x8*>(&P_lds[wid][buf][r16][g * 8]);
        // PV: D[q][d] += P[q][k] * Vt[d][k]
        for (int ds = 0; ds < 4; ds++) {
            size_t o = vt_base + (size_t)(ds * 16 + r16) * 2048 + k0 + g * 8;
            bf16x8 vh = *reinterpret_cast<const bf16x8*>(VTH + o);
            bf16x8 vl = *reinterpret_cast<const bf16x8*>(VTL + o);
            ctx[ds] = MFMA16(pa, vh, ctx[ds]);
            ctx[ds] = MFMA16(pa, vl, ctx[ds]);
        }
    }
    // epilogue: normalize by row-sum, write f32 out [b][s][h*64+d]
    float lr0 = __shfl(l_st, (lane & 48) | (g * 4 + 0));
    float lr1 = __shfl(l_st, (lane & 48) | (g * 4 + 1));
    float lr2 = __shfl(l_st, (lane & 48) | (g * 4 + 2));
    float lr3 = __shfl(l_st, (lane & 48) | (g * 4 + 3));
    for (int ds = 0; ds < 4; ds++) {
        int dcol = ds * 16 + r16;
        size_t base = ((size_t)b * 2048 + q0 + g * 4) * 1024 + h * 64 + dcol;
        out[base + 0 * 1024] = ctx[ds][0] / lr0;
        out[base + 1 * 1024] = ctx[ds][1] / lr1;
        out[base + 2 * 1024] = ctx[ds][2] / lr2;
        out[base + 3 * 1024] = ctx[ds][3] / lr3;
    }
}

// ---------------------------------------------------------------- launch
extern "C" void kernel_launch(void* const* d_in, const int* in_sizes, int n_in,
                              void* d_out, int out_size, void* d_ws, size_t ws_size,
                              hipStream_t stream) {
    const float* X  = (const float*)d_in[0];
    const int* mask = (const int*)d_in[1];
    const float* Wq = (const float*)d_in[2];
    const float* bq = (const float*)d_in[3];
    const float* Wk = (const float*)d_in[4];
    const float* bk = (const float*)d_in[5];
    const float* Wv = (const float*)d_in[6];
    const float* bv = (const float*)d_in[7];
    float* out = (float*)d_out;

    char* ws = (char*)d_ws;
    const size_t SZ_X = (size_t)4096 * 1024 * 2;      // 8 MB (bf16 plane of X)
    const size_t SZ_W = (size_t)1024 * 1024 * 2;      // 2 MB per W plane
    const size_t SZ_Q = (size_t)2 * 16 * 2048 * 64 * 2; // 8 MB per QKV plane
    unsigned short* XH  = (unsigned short*)(ws);
    unsigned short* XL  = (unsigned short*)(ws + SZ_X);
    unsigned short* WTH = (unsigned short*)(ws + 2 * SZ_X);
    unsigned short* WTL = (unsigned short*)(ws + 2 * SZ_X + 3 * SZ_W);
    unsigned short* QH  = (unsigned short*)(ws + 2 * SZ_X + 6 * SZ_W);
    unsigned short* QL  = (unsigned short*)(ws + 2 * SZ_X + 6 * SZ_W + 1 * SZ_Q);
    unsigned short* KH  = (unsigned short*)(ws + 2 * SZ_X + 6 * SZ_W + 2 * SZ_Q);
    unsigned short* KL  = (unsigned short*)(ws + 2 * SZ_X + 6 * SZ_W + 3 * SZ_Q);
    unsigned short* VTH = (unsigned short*)(ws + 2 * SZ_X + 6 * SZ_W + 4 * SZ_Q);
    unsigned short* VTL = (unsigned short*)(ws + 2 * SZ_X + 6 * SZ_W + 5 * SZ_Q);

    prep_x_kernel<<<4096, 256, 0, stream>>>(X, XH, XL);
    prep_w_kernel<<<dim3(16, 16, 3), 256, 0, stream>>>(Wq, Wk, Wv, WTH, WTL);
    qkv_gemm_kernel<<<dim3(64, 16, 3), 256, 0, stream>>>(XH, XL, WTH, WTL, bq, bk, bv,
                                                         QH, QL, KH, KL, VTH, VTL);
    attn_kernel<<<dim3(32, 32), 256, 0, stream>>>(QH, QL, KH, KL, VTH, VTL, mask, out);
}

// Round 2
// 467.873 us; speedup vs baseline: 1.7725x; 1.7725x over previous
//
#include <hip/hip_runtime.h>
#include <math.h>

typedef __attribute__((ext_vector_type(4))) float f32x4;
typedef __attribute__((ext_vector_type(16))) float f32x16;
typedef __attribute__((ext_vector_type(8))) short bf16x8;

#define MFMA16(a, b, c) __builtin_amdgcn_mfma_f32_16x16x32_bf16((a), (b), (c), 0, 0, 0)
#define MFMA32(a, b, c) __builtin_amdgcn_mfma_f32_32x32x16_bf16((a), (b), (c), 0, 0, 0)

__device__ __forceinline__ unsigned short f2bf(float f) {
    union { float f; unsigned u; } v; v.f = f;
    unsigned u = v.u;
    unsigned r = u + 0x7fffu + ((u >> 16) & 1u);
    return (unsigned short)(r >> 16);
}
__device__ __forceinline__ float bf2f(unsigned short h) {
    union { float f; unsigned u; } v; v.u = ((unsigned)h) << 16;
    return v.f;
}
__device__ __forceinline__ unsigned pk2(float a, float b) {
    return (unsigned)f2bf(a) | ((unsigned)f2bf(b) << 16);
}

#if defined(__has_builtin)
#if __has_builtin(__builtin_amdgcn_global_load_lds)
#define HAVE_GLL 1
#endif
#endif

__device__ __forceinline__ void gload16(const void* g, void* lds) {
#ifdef HAVE_GLL
    __builtin_amdgcn_global_load_lds(
        (const __attribute__((address_space(1))) void*)g,
        (__attribute__((address_space(3))) void*)lds, 16, 0, 0);
#else
    *(bf16x8*)lds = *(const bf16x8*)g;
#endif
}

// ---------------------------------------------------------------- prep X
__global__ __launch_bounds__(256) void prep_x_kernel(
    const float* __restrict__ X, unsigned short* __restrict__ XH,
    unsigned short* __restrict__ XL) {
    int i = (blockIdx.x * 256 + threadIdx.x) * 4;
    float4 v = *reinterpret_cast<const float4*>(X + i);
    ushort4 h, l;
    h.x = f2bf(v.x); l.x = f2bf(v.x - bf2f(h.x));
    h.y = f2bf(v.y); l.y = f2bf(v.y - bf2f(h.y));
    h.z = f2bf(v.z); l.z = f2bf(v.z - bf2f(h.z));
    h.w = f2bf(v.w); l.w = f2bf(v.w - bf2f(h.w));
    *reinterpret_cast<ushort4*>(XH + i) = h;
    *reinterpret_cast<ushort4*>(XL + i) = l;
}

// ---------------------------------------------------------------- prep W (transpose + hi/lo)
__global__ __launch_bounds__(256) void prep_w_kernel(
    const float* __restrict__ Wq, const float* __restrict__ Wk,
    const float* __restrict__ Wv, unsigned short* __restrict__ WTH,
    unsigned short* __restrict__ WTL) {
    __shared__ float T[64][65];
    int z = blockIdx.z;
    const float* W = (z == 0) ? Wq : ((z == 1) ? Wk : Wv);
    unsigned short* WH = WTH + (size_t)z * 1024 * 1024;
    unsigned short* WL = WTL + (size_t)z * 1024 * 1024;
    int k0 = blockIdx.x * 64, n0 = blockIdx.y * 64;
    int t = threadIdx.x;
    for (int i = 0; i < 4; i++) {
        int fid = t + i * 256;
        int rr = fid >> 4, cc = fid & 15;
        float4 v = *reinterpret_cast<const float4*>(W + (size_t)(k0 + rr) * 1024 + n0 + cc * 4);
        T[rr][cc * 4 + 0] = v.x; T[rr][cc * 4 + 1] = v.y;
        T[rr][cc * 4 + 2] = v.z; T[rr][cc * 4 + 3] = v.w;
    }
    __syncthreads();
    for (int i = 0; i < 4; i++) {
        int e = t + i * 256;
        int n = e >> 4, kq = (e & 15) * 4;
        ushort4 h, l;
        float a0 = T[kq + 0][n], a1 = T[kq + 1][n], a2 = T[kq + 2][n], a3 = T[kq + 3][n];
        h.x = f2bf(a0); l.x = f2bf(a0 - bf2f(h.x));
        h.y = f2bf(a1); l.y = f2bf(a1 - bf2f(h.y));
        h.z = f2bf(a2); l.z = f2bf(a2 - bf2f(h.z));
        h.w = f2bf(a3); l.w = f2bf(a3 - bf2f(h.w));
        size_t o = (size_t)(n0 + n) * 1024 + k0 + kq;
        *reinterpret_cast<ushort4*>(WH + o) = h;
        *reinterpret_cast<ushort4*>(WL + o) = l;
    }
}

// ---------------------------------------------------------------- QKV GEMM
__global__ __launch_bounds__(256) void qkv_gemm_kernel(
    const unsigned short* __restrict__ XH, const unsigned short* __restrict__ XL,
    const unsigned short* __restrict__ WTH, const unsigned short* __restrict__ WTL,
    const float* __restrict__ bq, const float* __restrict__ bk,
    const float* __restrict__ bv,
    unsigned short* __restrict__ QH, unsigned short* __restrict__ QL,
    unsigned short* __restrict__ KH, unsigned short* __restrict__ KL,
    unsigned short* __restrict__ VTH, unsigned short* __restrict__ VTL) {
    int z = blockIdx.z;
    const unsigned short* WH = WTH + (size_t)z * 1024 * 1024;
    const unsigned short* WL = WTL + (size_t)z * 1024 * 1024;
    const float* bias = (z == 0) ? bq : ((z == 1) ? bk : bv);
    int m0 = blockIdx.x * 64, n0 = blockIdx.y * 64;
    int tid = threadIdx.x, lane = tid & 63, wid = tid >> 6;
    int wm = wid >> 1, wn = wid & 1;
    int g = lane >> 4, r16 = lane & 15;

    f32x4 acc[2][2] = {};
    int mrow[2], nrow[2];
    for (int mi = 0; mi < 2; mi++) mrow[mi] = m0 + wm * 32 + mi * 16 + r16;
    for (int ni = 0; ni < 2; ni++) nrow[ni] = n0 + wn * 32 + ni * 16 + r16;

    for (int k0 = 0; k0 < 1024; k0 += 32) {
        int ko = k0 + g * 8;
        bf16x8 ah[2], al[2], bh[2], bl[2];
        for (int mi = 0; mi < 2; mi++) {
            ah[mi] = *reinterpret_cast<const bf16x8*>(XH + (size_t)mrow[mi] * 1024 + ko);
            al[mi] = *reinterpret_cast<const bf16x8*>(XL + (size_t)mrow[mi] * 1024 + ko);
        }
        for (int ni = 0; ni < 2; ni++) {
            bh[ni] = *reinterpret_cast<const bf16x8*>(WH + (size_t)nrow[ni] * 1024 + ko);
            bl[ni] = *reinterpret_cast<const bf16x8*>(WL + (size_t)nrow[ni] * 1024 + ko);
        }
        for (int mi = 0; mi < 2; mi++)
            for (int ni = 0; ni < 2; ni++) {
                acc[mi][ni] = MFMA16(ah[mi], bh[ni], acc[mi][ni]);
                acc[mi][ni] = MFMA16(ah[mi], bl[ni], acc[mi][ni]);
                acc[mi][ni] = MFMA16(al[mi], bh[ni], acc[mi][ni]);
            }
    }
    for (int mi = 0; mi < 2; mi++)
        for (int ni = 0; ni < 2; ni++)
            for (int r = 0; r < 4; r++) {
                int m = m0 + wm * 32 + mi * 16 + g * 4 + r;
                int n = n0 + wn * 32 + ni * 16 + r16;
                float val = acc[mi][ni][r] + bias[n];
                if (z == 0) val *= 0.125f;
                int b = m >> 11, s = m & 2047, hh = n >> 6, d = n & 63;
                unsigned short hi = f2bf(val);
                unsigned short lo = f2bf(val - bf2f(hi));
                if (z == 2) {
                    size_t o = ((size_t)(b * 16 + hh) * 64 + d) * 2048 + s;
                    VTH[o] = hi; VTL[o] = lo;
                } else {
                    size_t o = ((size_t)(b * 16 + hh) * 2048 + s) * 64 + d;
                    if (z == 0) { QH[o] = hi; QL[o] = lo; }
                    else        { KH[o] = hi; KL[o] = lo; }
                }
            }
}

// ---------------------------------------------------------------- attention (flash, 32x32 MFMA)
// grid (16, 32); block 256 = 4 waves, each wave owns 32 q-rows. KVBLK=64.
// K/V hi/lo staged in LDS (XOR-swizzled via per-lane global addrs), dbuf.
// Swapped QK^T: D[k][q] (q = lane&31); swapped PV: D[d][q] -> softmax state
// and ctx share lane layout (no cross-lane redistribution).
__global__ __launch_bounds__(256, 2) void attn_kernel(
    const unsigned short* __restrict__ QH, const unsigned short* __restrict__ QL,
    const unsigned short* __restrict__ KH, const unsigned short* __restrict__ KL,
    const unsigned short* __restrict__ VTH, const unsigned short* __restrict__ VTL,
    const int* __restrict__ mask, float* __restrict__ out) {
    __shared__ __align__(16) char smem[2][4][8192];  // [buf][KH,KL,VH,VL][64 rows x 128B]
    const int tid = threadIdx.x;
    const int lane = tid & 63, wid = tid >> 6;
    const int hi = lane >> 5, l31 = lane & 31;
    const int bh = blockIdx.y, b = bh >> 4, h = bh & 15;
    const size_t base = (size_t)bh * 2048 * 64;   // same stride for [s][d] and [d][s]
    const unsigned short* KHh = KH + base;
    const unsigned short* KLh = KL + base;
    const unsigned short* VHh = VTH + base;
    const unsigned short* VLh = VTL + base;
    const int qrow = blockIdx.x * 128 + wid * 32 + l31;
    const int* mrow = mask + b * 2048;

    // Q fragments (B operand): lane holds q = l31, k-elems = ks*16 + hi*8 .. +7
    bf16x8 qh[4], ql[4];
#pragma unroll
    for (int ks = 0; ks < 4; ++ks) {
        size_t o = base + (size_t)qrow * 64 + ks * 16 + hi * 8;
        qh[ks] = *reinterpret_cast<const bf16x8*>(QH + o);
        ql[ks] = *reinterpret_cast<const bf16x8*>(QL + o);
    }

    // staging: wave w stages tile w (0:KH 1:KL 2:VH 3:VL), 8KB each = 8x gload16.
    // LDS linear (row, c) <- global (row, c ^ ((row&7)<<4)) : XOR via source addr.
    const int lr = (lane >> 3) & 7, c16 = lane & 7;
    const int gce = (c16 ^ lr) << 3;  // element col in source row
    const unsigned short* mys = (wid == 0) ? KHh : (wid == 1) ? KLh : (wid == 2) ? VHh : VLh;
    const int rstr = (wid < 2) ? 64 : 2048;

    f32x16 ctx[2] = {};
    float m_st = -INFINITY, l_st = 0.f;

#define STAGE(BUFI, K0)                                                              \
    {                                                                                \
        char* dst = &smem[(BUFI)][wid][0];                                           \
        size_t koff = (wid < 2) ? (size_t)(K0) * 64 : (size_t)(K0);                  \
        _Pragma("unroll")                                                            \
        for (int i = 0; i < 8; ++i) {                                                \
            int r = i * 8 + lr;                                                      \
            gload16(mys + koff + (size_t)r * rstr + gce, dst + i * 1024 + lane * 16);\
        }                                                                            \
    }

    STAGE(0, 0);
    for (int ch = 0; ch < 32; ++ch) {
        const int k0 = ch * 64;
        const int buf = ch & 1;
        if (ch < 31) {
            STAGE(buf ^ 1, k0 + 64);
#ifdef HAVE_GLL
            asm volatile("s_waitcnt vmcnt(8)" ::: "memory");
#endif
        } else {
#ifdef HAVE_GLL
            asm volatile("s_waitcnt vmcnt(0)" ::: "memory");
#endif
        }
        __syncthreads();
        const char* bKH = &smem[buf][0][0];
        const char* bKL = &smem[buf][1][0];
        const char* bVH = &smem[buf][2][0];
        const char* bVL = &smem[buf][3][0];
        const int swz = (l31 & 7) << 4;

        // ---- QK^T (swapped): A = K rows, B = Q
        f32x16 sc[2];
#pragma unroll
        for (int kt = 0; kt < 2; ++kt) {
            const char* rH = bKH + (kt * 32 + l31) * 128;
            const char* rL = bKL + (kt * 32 + l31) * 128;
            f32x16 a = {};
#pragma unroll
            for (int ks = 0; ks < 4; ++ks) {
                int cb = (ks * 32 + hi * 16) ^ swz;
                bf16x8 kh = *(const bf16x8*)(rH + cb);
                bf16x8 kl = *(const bf16x8*)(rL + cb);
                a = MFMA32(kh, qh[ks], a);
                a = MFMA32(kh, ql[ks], a);
                a = MFMA32(kl, qh[ks], a);
            }
            sc[kt] = a;
        }

        // ---- online softmax (per-lane q; k_local = (r&3)+8*(r>>2)+4*hi+32*kt)
        float p[32];
#pragma unroll
        for (int kt = 0; kt < 2; ++kt)
#pragma unroll
            for (int r = 0; r < 16; ++r) p[kt * 16 + r] = sc[kt][r];
        float mc = p[0];
#pragma unroll
        for (int i = 1; i < 32; ++i) mc = fmaxf(mc, p[i]);
        mc = fmaxf(mc, __shfl_xor(mc, 32));
        float m_new = fmaxf(m_st, mc);
        float fac = __expf(m_st - m_new);
        float psum = 0.f;
#pragma unroll
        for (int kt = 0; kt < 2; ++kt)
#pragma unroll
            for (int G = 0; G < 4; ++G) {
                int4 mk = *reinterpret_cast<const int4*>(mrow + k0 + kt * 32 + 8 * G + 4 * hi);
                int bo = kt * 16 + G * 4;
                float e0 = mk.x ? __expf(p[bo + 0] - m_new) : 0.f;
                float e1 = mk.y ? __expf(p[bo + 1] - m_new) : 0.f;
                float e2 = mk.z ? __expf(p[bo + 2] - m_new) : 0.f;
                float e3 = mk.w ? __expf(p[bo + 3] - m_new) : 0.f;
                p[bo + 0] = e0; p[bo + 1] = e1; p[bo + 2] = e2; p[bo + 3] = e3;
                psum += e0 + e1 + e2 + e3;
            }
        psum += __shfl_xor(psum, 32);
        l_st = l_st * fac + psum;
        m_st = m_new;
        ctx[0] *= fac; ctx[1] *= fac;

        // ---- pack P into PV B-fragments (in-register, halves exchange)
        bf16x8 pf[4];
#pragma unroll
        for (int kt = 0; kt < 2; ++kt) {
            int bo = kt * 16;
            unsigned a0 = pk2(p[bo + 0], p[bo + 1]),  a1 = pk2(p[bo + 2], p[bo + 3]);
            unsigned b0 = pk2(p[bo + 4], p[bo + 5]),  b1 = pk2(p[bo + 6], p[bo + 7]);
            unsigned c0 = pk2(p[bo + 8], p[bo + 9]),  c1 = pk2(p[bo + 10], p[bo + 11]);
            unsigned d0 = pk2(p[bo + 12], p[bo + 13]), d1 = pk2(p[bo + 14], p[bo + 15]);
            unsigned ta0 = __shfl_xor((int)a0, 32), ta1 = __shfl_xor((int)a1, 32);
            unsigned tb0 = __shfl_xor((int)b0, 32), tb1 = __shfl_xor((int)b1, 32);
            unsigned tc0 = __shfl_xor((int)c0, 32), tc1 = __shfl_xor((int)c1, 32);
            unsigned td0 = __shfl_xor((int)d0, 32), td1 = __shfl_xor((int)d1, 32);
            union { unsigned u[4]; bf16x8 v; } f0, f1;
            f0.u[0] = hi ? tb0 : a0; f0.u[1] = hi ? tb1 : a1;
            f0.u[2] = hi ? b0 : ta0; f0.u[3] = hi ? b1 : ta1;
            f1.u[0] = hi ? td0 : c0; f1.u[1] = hi ? td1 : c1;
            f1.u[2] = hi ? d0 : tc0; f1.u[3] = hi ? d1 : tc1;
            pf[kt * 2 + 0] = f0.v; pf[kt * 2 + 1] = f1.v;
        }

        // ---- PV (swapped): A = Vt rows (d), B = P  ->  D[d][q]
#pragma unroll
        for (int dt = 0; dt < 2; ++dt) {
            const char* rH = bVH + (dt * 32 + l31) * 128;
            const char* rL = bVL + (dt * 32 + l31) * 128;
            f32x16 a = ctx[dt];
#pragma unroll
            for (int ks = 0; ks < 4; ++ks) {
                int cb = (ks * 32 + hi * 16) ^ swz;
                bf16x8 vh = *(const bf16x8*)(rH + cb);
                bf16x8 vl = *(const bf16x8*)(rL + cb);
                a = MFMA32(vh, pf[ks], a);
                a = MFMA32(vl, pf[ks], a);
            }
            ctx[dt] = a;
        }
        __syncthreads();
    }

    // ---- epilogue: lane q = l31; d = dt*32 + 8*G + 4*hi + j
    float inv_l = 1.0f / l_st;
    size_t ob0 = ((size_t)b * 2048 + qrow) * 1024 + h * 64 + 4 * hi;
#pragma unroll
    for (int dt = 0; dt < 2; ++dt)
#pragma unroll
        for (int G = 0; G < 4; ++G) {
            float4 st;
            st.x = ctx[dt][G * 4 + 0] * inv_l;
            st.y = ctx[dt][G * 4 + 1] * inv_l;
            st.z = ctx[dt][G * 4 + 2] * inv_l;
            st.w = ctx[dt][G * 4 + 3] * inv_l;
            *reinterpret_cast<float4*>(out + ob0 + dt * 32 + 8 * G) = st;
        }
}

// ---------------------------------------------------------------- launch
extern "C" void kernel_launch(void* const* d_in, const int* in_sizes, int n_in,
                              void* d_out, int out_size, void* d_ws, size_t ws_size,
                              hipStream_t stream) {
    const float* X  = (const float*)d_in[0];
    const int* mask = (const int*)d_in[1];
    const float* Wq = (const float*)d_in[2];
    const float* bq = (const float*)d_in[3];
    const float* Wk = (const float*)d_in[4];
    const float* bk = (const float*)d_in[5];
    const float* Wv = (const float*)d_in[6];
    const float* bv = (const float*)d_in[7];
    float* out = (float*)d_out;

    char* ws = (char*)d_ws;
    const size_t SZ_X = (size_t)4096 * 1024 * 2;
    const size_t SZ_W = (size_t)1024 * 1024 * 2;
    const size_t SZ_Q = (size_t)2 * 16 * 2048 * 64 * 2;
    unsigned short* XH  = (unsigned short*)(ws);
    unsigned short* XL  = (unsigned short*)(ws + SZ_X);
    unsigned short* WTH = (unsigned short*)(ws + 2 * SZ_X);
    unsigned short* WTL = (unsigned short*)(ws + 2 * SZ_X + 3 * SZ_W);
    unsigned short* QH  = (unsigned short*)(ws + 2 * SZ_X + 6 * SZ_W);
    unsigned short* QL  = (unsigned short*)(ws + 2 * SZ_X + 6 * SZ_W + 1 * SZ_Q);
    unsigned short* KH  = (unsigned short*)(ws + 2 * SZ_X + 6 * SZ_W + 2 * SZ_Q);
    unsigned short* KL  = (unsigned short*)(ws + 2 * SZ_X + 6 * SZ_W + 3 * SZ_Q);
    unsigned short* VTH = (unsigned short*)(ws + 2 * SZ_X + 6 * SZ_W + 4 * SZ_Q);
    unsigned short* VTL = (unsigned short*)(ws + 2 * SZ_X + 6 * SZ_W + 5 * SZ_Q);

    prep_x_kernel<<<4096, 256, 0, stream>>>(X, XH, XL);
    prep_w_kernel<<<dim3(16, 16, 3), 256, 0, stream>>>(Wq, Wk, Wv, WTH, WTL);
    qkv_gemm_kernel<<<dim3(64, 16, 3), 256, 0, stream>>>(XH, XL, WTH, WTL, bq, bk, bv,
                                                         QH, QL, KH, KL, VTH, VTL);
    attn_kernel<<<dim3(16, 32), 256, 0, stream>>>(QH, QL, KH, KL, VTH, VTL, mask, out);
}

// Round 3
// 233.087 us; speedup vs baseline: 3.5579x; 2.0073x over previous
//
#include <hip/hip_runtime.h>
#include <math.h>

typedef __attribute__((ext_vector_type(4))) float f32x4;
typedef __attribute__((ext_vector_type(16))) float f32x16;
typedef __attribute__((ext_vector_type(8))) short bf16x8;

#define MFMA16(a, b, c) __builtin_amdgcn_mfma_f32_16x16x32_bf16((a), (b), (c), 0, 0, 0)
#define MFMA32(a, b, c) __builtin_amdgcn_mfma_f32_32x32x16_bf16((a), (b), (c), 0, 0, 0)

__device__ __forceinline__ unsigned short f2bf(float f) {
    union { float f; unsigned u; } v; v.f = f;
    unsigned u = v.u;
    unsigned r = u + 0x7fffu + ((u >> 16) & 1u);
    return (unsigned short)(r >> 16);
}
__device__ __forceinline__ float bf2f(unsigned short h) {
    union { float f; unsigned u; } v; v.u = ((unsigned)h) << 16;
    return v.f;
}
__device__ __forceinline__ unsigned pk2(float a, float b) {
    return (unsigned)f2bf(a) | ((unsigned)f2bf(b) << 16);
}

#if defined(__has_builtin)
#if __has_builtin(__builtin_amdgcn_global_load_lds)
#define HAVE_GLL 1
#endif
#endif

__device__ __forceinline__ void gload16(const void* g, void* lds) {
#ifdef HAVE_GLL
    __builtin_amdgcn_global_load_lds(
        (const __attribute__((address_space(1))) void*)g,
        (__attribute__((address_space(3))) void*)lds, 16, 0, 0);
#else
    *(bf16x8*)lds = *(const bf16x8*)g;
#endif
}

// ---------------------------------------------------------------- prep X
__global__ __launch_bounds__(256) void prep_x_kernel(
    const float* __restrict__ X, unsigned short* __restrict__ XH,
    unsigned short* __restrict__ XL) {
    int i = (blockIdx.x * 256 + threadIdx.x) * 4;
    float4 v = *reinterpret_cast<const float4*>(X + i);
    ushort4 h, l;
    h.x = f2bf(v.x); l.x = f2bf(v.x - bf2f(h.x));
    h.y = f2bf(v.y); l.y = f2bf(v.y - bf2f(h.y));
    h.z = f2bf(v.z); l.z = f2bf(v.z - bf2f(h.z));
    h.w = f2bf(v.w); l.w = f2bf(v.w - bf2f(h.w));
    *reinterpret_cast<ushort4*>(XH + i) = h;
    *reinterpret_cast<ushort4*>(XL + i) = l;
}

// ---------------------------------------------------------------- prep W (transpose + hi/lo)
__global__ __launch_bounds__(256) void prep_w_kernel(
    const float* __restrict__ Wq, const float* __restrict__ Wk,
    const float* __restrict__ Wv, unsigned short* __restrict__ WTH,
    unsigned short* __restrict__ WTL) {
    __shared__ float T[64][65];
    int z = blockIdx.z;
    const float* W = (z == 0) ? Wq : ((z == 1) ? Wk : Wv);
    unsigned short* WH = WTH + (size_t)z * 1024 * 1024;
    unsigned short* WL = WTL + (size_t)z * 1024 * 1024;
    int k0 = blockIdx.x * 64, n0 = blockIdx.y * 64;
    int t = threadIdx.x;
    for (int i = 0; i < 4; i++) {
        int fid = t + i * 256;
        int rr = fid >> 4, cc = fid & 15;
        float4 v = *reinterpret_cast<const float4*>(W + (size_t)(k0 + rr) * 1024 + n0 + cc * 4);
        T[rr][cc * 4 + 0] = v.x; T[rr][cc * 4 + 1] = v.y;
        T[rr][cc * 4 + 2] = v.z; T[rr][cc * 4 + 3] = v.w;
    }
    __syncthreads();
    for (int i = 0; i < 4; i++) {
        int e = t + i * 256;
        int n = e >> 4, kq = (e & 15) * 4;
        ushort4 h, l;
        float a0 = T[kq + 0][n], a1 = T[kq + 1][n], a2 = T[kq + 2][n], a3 = T[kq + 3][n];
        h.x = f2bf(a0); l.x = f2bf(a0 - bf2f(h.x));
        h.y = f2bf(a1); l.y = f2bf(a1 - bf2f(h.y));
        h.z = f2bf(a2); l.z = f2bf(a2 - bf2f(h.z));
        h.w = f2bf(a3); l.w = f2bf(a3 - bf2f(h.w));
        size_t o = (size_t)(n0 + n) * 1024 + k0 + kq;
        *reinterpret_cast<ushort4*>(WH + o) = h;
        *reinterpret_cast<ushort4*>(WL + o) = l;
    }
}

// ---------------------------------------------------------------- QKV GEMM (m97 structure)
// 128x128 tile, BK=32, 4 waves x (64x64). XH/XL/WH/WL staged in LDS via
// global_load_lds w16, double-buffered, counted vmcnt(8).
__global__ __launch_bounds__(256, 2) void qkv_gemm_kernel(
    const unsigned short* __restrict__ XH, const unsigned short* __restrict__ XL,
    const unsigned short* __restrict__ WTH, const unsigned short* __restrict__ WTL,
    const float* __restrict__ bq, const float* __restrict__ bk,
    const float* __restrict__ bv,
    unsigned short* __restrict__ QH, unsigned short* __restrict__ QL,
    unsigned short* __restrict__ KH, unsigned short* __restrict__ KL,
    unsigned short* __restrict__ VTH, unsigned short* __restrict__ VTL) {
    __shared__ __align__(16) char smem[2][4][8192];  // [buf][XH,XL,WH,WL][128 rows x 64B]
    int z = blockIdx.z;
    const unsigned short* WH = WTH + (size_t)z * 1024 * 1024;
    const unsigned short* WL = WTL + (size_t)z * 1024 * 1024;
    const float* bias = (z == 0) ? bq : ((z == 1) ? bk : bv);
    const int m0 = blockIdx.x * 128, n0 = blockIdx.y * 128;
    const int tid = threadIdx.x, lane = tid & 63, wid = tid >> 6;
    const int wr = wid >> 1, wc = wid & 1;          // wave tile (64x64)
    const int g = lane >> 4, r16 = lane & 15;

    // staging geometry: thread t covers row t>>2 (per 64-row pass), col (t&3)*8
    const int srow = tid >> 2, scol = (tid & 3) * 8;

    f32x4 acc[4][4] = {};

#define QSTAGE(BUFI, K0)                                                             \
    {                                                                                \
        _Pragma("unroll")                                                            \
        for (int pass = 0; pass < 2; ++pass) {                                       \
            int row = pass * 64 + srow;                                              \
            size_t xo = (size_t)(m0 + row) * 1024 + (K0) + scol;                     \
            size_t wo = (size_t)(n0 + row) * 1024 + (K0) + scol;                     \
            char* d0 = &smem[(BUFI)][0][0] + pass * 4096 + tid * 16;                 \
            char* d1 = &smem[(BUFI)][1][0] + pass * 4096 + tid * 16;                 \
            char* d2 = &smem[(BUFI)][2][0] + pass * 4096 + tid * 16;                 \
            char* d3 = &smem[(BUFI)][3][0] + pass * 4096 + tid * 16;                 \
            gload16(XH + xo, d0);                                                    \
            gload16(XL + xo, d1);                                                    \
            gload16(WH + wo, d2);                                                    \
            gload16(WL + wo, d3);                                                    \
        }                                                                            \
    }

    QSTAGE(0, 0);
    for (int ks = 0; ks < 32; ++ks) {
        const int buf = ks & 1;
        if (ks < 31) {
            QSTAGE(buf ^ 1, (ks + 1) * 32);
#ifdef HAVE_GLL
            asm volatile("s_waitcnt vmcnt(8)" ::: "memory");
#endif
        } else {
#ifdef HAVE_GLL
            asm volatile("s_waitcnt vmcnt(0)" ::: "memory");
#endif
        }
        __syncthreads();
        const char* bXH = &smem[buf][0][0];
        const char* bXL = &smem[buf][1][0];
        const char* bWH = &smem[buf][2][0];
        const char* bWL = &smem[buf][3][0];

        bf16x8 ah[4], al[4], bh[4], bl[4];
#pragma unroll
        for (int mi = 0; mi < 4; ++mi) {
            int off = (wr * 64 + mi * 16 + r16) * 64 + g * 16;
            ah[mi] = *(const bf16x8*)(bXH + off);
            al[mi] = *(const bf16x8*)(bXL + off);
        }
#pragma unroll
        for (int ni = 0; ni < 4; ++ni) {
            int off = (wc * 64 + ni * 16 + r16) * 64 + g * 16;
            bh[ni] = *(const bf16x8*)(bWH + off);
            bl[ni] = *(const bf16x8*)(bWL + off);
        }
#pragma unroll
        for (int mi = 0; mi < 4; ++mi)
#pragma unroll
            for (int ni = 0; ni < 4; ++ni) {
                acc[mi][ni] = MFMA16(ah[mi], bh[ni], acc[mi][ni]);
                acc[mi][ni] = MFMA16(ah[mi], bl[ni], acc[mi][ni]);
                acc[mi][ni] = MFMA16(al[mi], bh[ni], acc[mi][ni]);
            }
        __syncthreads();
    }

    // epilogue: frag D row = g*4+r (m), col = r16 (n)
#pragma unroll
    for (int mi = 0; mi < 4; ++mi)
#pragma unroll
        for (int ni = 0; ni < 4; ++ni)
#pragma unroll
            for (int r = 0; r < 4; ++r) {
                int m = m0 + wr * 64 + mi * 16 + g * 4 + r;
                int n = n0 + wc * 64 + ni * 16 + r16;
                float val = acc[mi][ni][r] + bias[n];
                if (z == 0) val *= 0.125f;
                int b = m >> 11, s = m & 2047, hh = n >> 6, d = n & 63;
                unsigned short hi = f2bf(val);
                unsigned short lo = f2bf(val - bf2f(hi));
                if (z == 2) {
                    size_t o = ((size_t)(b * 16 + hh) * 64 + d) * 2048 + s;
                    VTH[o] = hi; VTL[o] = lo;
                } else {
                    size_t o = ((size_t)(b * 16 + hh) * 2048 + s) * 64 + d;
                    if (z == 0) { QH[o] = hi; QL[o] = lo; }
                    else        { KH[o] = hi; KL[o] = lo; }
                }
            }
}

// ---------------------------------------------------------------- attention (flash, 32x32 MFMA)
// grid (16, 32); block 256 = 4 waves, each wave owns 32 q-rows. KVBLK=64.
__global__ __launch_bounds__(256, 2) void attn_kernel(
    const unsigned short* __restrict__ QH, const unsigned short* __restrict__ QL,
    const unsigned short* __restrict__ KH, const unsigned short* __restrict__ KL,
    const unsigned short* __restrict__ VTH, const unsigned short* __restrict__ VTL,
    const int* __restrict__ mask, float* __restrict__ out) {
    __shared__ __align__(16) char smem[2][4][8192];  // [buf][KH,KL,VH,VL][64 rows x 128B]
    const int tid = threadIdx.x;
    const int lane = tid & 63, wid = tid >> 6;
    const int hi = lane >> 5, l31 = lane & 31;
    const int bh = blockIdx.y, b = bh >> 4, h = bh & 15;
    const size_t base = (size_t)bh * 2048 * 64;
    const unsigned short* KHh = KH + base;
    const unsigned short* KLh = KL + base;
    const unsigned short* VHh = VTH + base;
    const unsigned short* VLh = VTL + base;
    const int qrow = blockIdx.x * 128 + wid * 32 + l31;
    const int* mrow = mask + b * 2048;

    bf16x8 qh[4], ql[4];
#pragma unroll
    for (int ks = 0; ks < 4; ++ks) {
        size_t o = base + (size_t)qrow * 64 + ks * 16 + hi * 8;
        qh[ks] = *reinterpret_cast<const bf16x8*>(QH + o);
        ql[ks] = *reinterpret_cast<const bf16x8*>(QL + o);
    }

    const int lr = (lane >> 3) & 7, c16 = lane & 7;
    const int gce = (c16 ^ lr) << 3;
    const unsigned short* mys = (wid == 0) ? KHh : (wid == 1) ? KLh : (wid == 2) ? VHh : VLh;
    const int rstr = (wid < 2) ? 64 : 2048;

    f32x16 ctx[2] = {};
    float m_st = -INFINITY, l_st = 0.f;

#define STAGE(BUFI, K0)                                                              \
    {                                                                                \
        char* dst = &smem[(BUFI)][wid][0];                                           \
        size_t koff = (wid < 2) ? (size_t)(K0) * 64 : (size_t)(K0);                  \
        _Pragma("unroll")                                                            \
        for (int i = 0; i < 8; ++i) {                                                \
            int r = i * 8 + lr;                                                      \
            gload16(mys + koff + (size_t)r * rstr + gce, dst + i * 1024 + lane * 16);\
        }                                                                            \
    }

    STAGE(0, 0);
    for (int ch = 0; ch < 32; ++ch) {
        const int k0 = ch * 64;
        const int buf = ch & 1;
        if (ch < 31) {
            STAGE(buf ^ 1, k0 + 64);
#ifdef HAVE_GLL
            asm volatile("s_waitcnt vmcnt(8)" ::: "memory");
#endif
        } else {
#ifdef HAVE_GLL
            asm volatile("s_waitcnt vmcnt(0)" ::: "memory");
#endif
        }
        __syncthreads();
        const char* bKH = &smem[buf][0][0];
        const char* bKL = &smem[buf][1][0];
        const char* bVH = &smem[buf][2][0];
        const char* bVL = &smem[buf][3][0];
        const int swz = (l31 & 7) << 4;

        f32x16 sc[2];
#pragma unroll
        for (int kt = 0; kt < 2; ++kt) {
            const char* rH = bKH + (kt * 32 + l31) * 128;
            const char* rL = bKL + (kt * 32 + l31) * 128;
            f32x16 a = {};
#pragma unroll
            for (int ks = 0; ks < 4; ++ks) {
                int cb = (ks * 32 + hi * 16) ^ swz;
                bf16x8 kh = *(const bf16x8*)(rH + cb);
                bf16x8 kl = *(const bf16x8*)(rL + cb);
                a = MFMA32(kh, qh[ks], a);
                a = MFMA32(kh, ql[ks], a);
                a = MFMA32(kl, qh[ks], a);
            }
            sc[kt] = a;
        }

        float p[32];
#pragma unroll
        for (int kt = 0; kt < 2; ++kt)
#pragma unroll
            for (int r = 0; r < 16; ++r) p[kt * 16 + r] = sc[kt][r];
        float mc = p[0];
#pragma unroll
        for (int i = 1; i < 32; ++i) mc = fmaxf(mc, p[i]);
        mc = fmaxf(mc, __shfl_xor(mc, 32));
        float m_new = fmaxf(m_st, mc);
        float fac = __expf(m_st - m_new);
        float psum = 0.f;
#pragma unroll
        for (int kt = 0; kt < 2; ++kt)
#pragma unroll
            for (int G = 0; G < 4; ++G) {
                int4 mk = *reinterpret_cast<const int4*>(mrow + k0 + kt * 32 + 8 * G + 4 * hi);
                int bo = kt * 16 + G * 4;
                float e0 = mk.x ? __expf(p[bo + 0] - m_new) : 0.f;
                float e1 = mk.y ? __expf(p[bo + 1] - m_new) : 0.f;
                float e2 = mk.z ? __expf(p[bo + 2] - m_new) : 0.f;
                float e3 = mk.w ? __expf(p[bo + 3] - m_new) : 0.f;
                p[bo + 0] = e0; p[bo + 1] = e1; p[bo + 2] = e2; p[bo + 3] = e3;
                psum += e0 + e1 + e2 + e3;
            }
        psum += __shfl_xor(psum, 32);
        l_st = l_st * fac + psum;
        m_st = m_new;
        ctx[0] *= fac; ctx[1] *= fac;

        bf16x8 pf[4];
#pragma unroll
        for (int kt = 0; kt < 2; ++kt) {
            int bo = kt * 16;
            unsigned a0 = pk2(p[bo + 0], p[bo + 1]),  a1 = pk2(p[bo + 2], p[bo + 3]);
            unsigned b0 = pk2(p[bo + 4], p[bo + 5]),  b1 = pk2(p[bo + 6], p[bo + 7]);
            unsigned c0 = pk2(p[bo + 8], p[bo + 9]),  c1 = pk2(p[bo + 10], p[bo + 11]);
            unsigned d0 = pk2(p[bo + 12], p[bo + 13]), d1 = pk2(p[bo + 14], p[bo + 15]);
            unsigned ta0 = __shfl_xor((int)a0, 32), ta1 = __shfl_xor((int)a1, 32);
            unsigned tb0 = __shfl_xor((int)b0, 32), tb1 = __shfl_xor((int)b1, 32);
            unsigned tc0 = __shfl_xor((int)c0, 32), tc1 = __shfl_xor((int)c1, 32);
            unsigned td0 = __shfl_xor((int)d0, 32), td1 = __shfl_xor((int)d1, 32);
            union { unsigned u[4]; bf16x8 v; } f0, f1;
            f0.u[0] = hi ? tb0 : a0; f0.u[1] = hi ? tb1 : a1;
            f0.u[2] = hi ? b0 : ta0; f0.u[3] = hi ? b1 : ta1;
            f1.u[0] = hi ? td0 : c0; f1.u[1] = hi ? td1 : c1;
            f1.u[2] = hi ? d0 : tc0; f1.u[3] = hi ? d1 : tc1;
            pf[kt * 2 + 0] = f0.v; pf[kt * 2 + 1] = f1.v;
        }

#pragma unroll
        for (int dt = 0; dt < 2; ++dt) {
            const char* rH = bVH + (dt * 32 + l31) * 128;
            const char* rL = bVL + (dt * 32 + l31) * 128;
            f32x16 a = ctx[dt];
#pragma unroll
            for (int ks = 0; ks < 4; ++ks) {
                int cb = (ks * 32 + hi * 16) ^ swz;
                bf16x8 vh = *(const bf16x8*)(rH + cb);
                bf16x8 vl = *(const bf16x8*)(rL + cb);
                a = MFMA32(vh, pf[ks], a);
                a = MFMA32(vl, pf[ks], a);
            }
            ctx[dt] = a;
        }
        __syncthreads();
    }

    float inv_l = 1.0f / l_st;
    size_t ob0 = ((size_t)b * 2048 + qrow) * 1024 + h * 64 + 4 * hi;
#pragma unroll
    for (int dt = 0; dt < 2; ++dt)
#pragma unroll
        for (int G = 0; G < 4; ++G) {
            float4 st;
            st.x = ctx[dt][G * 4 + 0] * inv_l;
            st.y = ctx[dt][G * 4 + 1] * inv_l;
            st.z = ctx[dt][G * 4 + 2] * inv_l;
            st.w = ctx[dt][G * 4 + 3] * inv_l;
            *reinterpret_cast<float4*>(out + ob0 + dt * 32 + 8 * G) = st;
        }
}

// ---------------------------------------------------------------- launch
extern "C" void kernel_launch(void* const* d_in, const int* in_sizes, int n_in,
                              void* d_out, int out_size, void* d_ws, size_t ws_size,
                              hipStream_t stream) {
    const float* X  = (const float*)d_in[0];
    const int* mask = (const int*)d_in[1];
    const float* Wq = (const float*)d_in[2];
    const float* bq = (const float*)d_in[3];
    const float* Wk = (const float*)d_in[4];
    const float* bk = (const float*)d_in[5];
    const float* Wv = (const float*)d_in[6];
    const float* bv = (const float*)d_in[7];
    float* out = (float*)d_out;

    char* ws = (char*)d_ws;
    const size_t SZ_X = (size_t)4096 * 1024 * 2;
    const size_t SZ_W = (size_t)1024 * 1024 * 2;
    const size_t SZ_Q = (size_t)2 * 16 * 2048 * 64 * 2;
    unsigned short* XH  = (unsigned short*)(ws);
    unsigned short* XL  = (unsigned short*)(ws + SZ_X);
    unsigned short* WTH = (unsigned short*)(ws + 2 * SZ_X);
    unsigned short* WTL = (unsigned short*)(ws + 2 * SZ_X + 3 * SZ_W);
    unsigned short* QH  = (unsigned short*)(ws + 2 * SZ_X + 6 * SZ_W);
    unsigned short* QL  = (unsigned short*)(ws + 2 * SZ_X + 6 * SZ_W + 1 * SZ_Q);
    unsigned short* KH  = (unsigned short*)(ws + 2 * SZ_X + 6 * SZ_W + 2 * SZ_Q);
    unsigned short* KL  = (unsigned short*)(ws + 2 * SZ_X + 6 * SZ_W + 3 * SZ_Q);
    unsigned short* VTH = (unsigned short*)(ws + 2 * SZ_X + 6 * SZ_W + 4 * SZ_Q);
    unsigned short* VTL = (unsigned short*)(ws + 2 * SZ_X + 6 * SZ_W + 5 * SZ_Q);

    prep_x_kernel<<<4096, 256, 0, stream>>>(X, XH, XL);
    prep_w_kernel<<<dim3(16, 16, 3), 256, 0, stream>>>(Wq, Wk, Wv, WTH, WTL);
    qkv_gemm_kernel<<<dim3(32, 8, 3), 256, 0, stream>>>(XH, XL, WTH, WTL, bq, bk, bv,
                                                        QH, QL, KH, KL, VTH, VTL);
    attn_kernel<<<dim3(16, 32), 256, 0, stream>>>(QH, QL, KH, KL, VTH, VTL, mask, out);
}

// Round 5
// 141.998 us; speedup vs baseline: 5.8402x; 1.6415x over previous
//
#include <hip/hip_runtime.h>
#include <math.h>

typedef __attribute__((ext_vector_type(4))) float f32x4;
typedef __attribute__((ext_vector_type(16))) float f32x16;
typedef _Float16 f16x8 __attribute__((ext_vector_type(8)));
typedef __fp16 fp16x2 __attribute__((ext_vector_type(2)));

#define MFMA16(a, b, c) __builtin_amdgcn_mfma_f32_16x16x32_f16((a), (b), (c), 0, 0, 0)
#define MFMA32(a, b, c) __builtin_amdgcn_mfma_f32_32x32x16_f16((a), (b), (c), 0, 0, 0)

__device__ __forceinline__ unsigned short f2h(float f) {
    union { _Float16 h; unsigned short u; } v; v.h = (_Float16)f; return v.u;
}
__device__ __forceinline__ unsigned pk2f(float a, float b) {
    union { fp16x2 h; unsigned u; } v; v.h = __builtin_amdgcn_cvt_pkrtz(a, b); return v.u;
}

#if defined(__has_builtin)
#if __has_builtin(__builtin_amdgcn_global_load_lds)
#define HAVE_GLL 1
#endif
#endif

__device__ __forceinline__ void gload16(const void* g, void* lds) {
#ifdef HAVE_GLL
    __builtin_amdgcn_global_load_lds(
        (const __attribute__((address_space(1))) void*)g,
        (__attribute__((address_space(3))) void*)lds, 16, 0, 0);
#else
    *(f16x8*)lds = *(const f16x8*)g;
#endif
}

// ---------------------------------------------------------------- prep X (f32 -> f16)
__global__ __launch_bounds__(256) void prep_x_kernel(
    const float* __restrict__ X, unsigned short* __restrict__ XF) {
    int i = (blockIdx.x * 256 + threadIdx.x) * 4;
    float4 v = *reinterpret_cast<const float4*>(X + i);
    ushort4 h;
    h.x = f2h(v.x); h.y = f2h(v.y); h.z = f2h(v.z); h.w = f2h(v.w);
    *reinterpret_cast<ushort4*>(XF + i) = h;
}

// ---------------------------------------------------------------- prep W (transpose + f16)
__global__ __launch_bounds__(256) void prep_w_kernel(
    const float* __restrict__ Wq, const float* __restrict__ Wk,
    const float* __restrict__ Wv, unsigned short* __restrict__ WT) {
    __shared__ float T[64][65];
    int z = blockIdx.z;
    const float* W = (z == 0) ? Wq : ((z == 1) ? Wk : Wv);
    unsigned short* Wo = WT + (size_t)z * 1024 * 1024;
    int k0 = blockIdx.x * 64, n0 = blockIdx.y * 64;
    int t = threadIdx.x;
    for (int i = 0; i < 4; i++) {
        int fid = t + i * 256;
        int rr = fid >> 4, cc = fid & 15;
        float4 v = *reinterpret_cast<const float4*>(W + (size_t)(k0 + rr) * 1024 + n0 + cc * 4);
        T[rr][cc * 4 + 0] = v.x; T[rr][cc * 4 + 1] = v.y;
        T[rr][cc * 4 + 2] = v.z; T[rr][cc * 4 + 3] = v.w;
    }
    __syncthreads();
    for (int i = 0; i < 4; i++) {
        int e = t + i * 256;
        int n = e >> 4, kq = (e & 15) * 4;
        ushort4 h;
        h.x = f2h(T[kq + 0][n]); h.y = f2h(T[kq + 1][n]);
        h.z = f2h(T[kq + 2][n]); h.w = f2h(T[kq + 3][n]);
        size_t o = (size_t)(n0 + n) * 1024 + k0 + kq;
        *reinterpret_cast<ushort4*>(Wo + o) = h;
    }
}

// ---------------------------------------------------------------- QKV GEMM (f16, m97 structure)
// 128x128 tile, BK=64, 4 waves x (64x64), 2 LDS planes (X, W) XOR-swizzled,
// global_load_lds w16, double-buffered, counted vmcnt(8).
__global__ __launch_bounds__(256, 2) void qkv_gemm_kernel(
    const unsigned short* __restrict__ XF, const unsigned short* __restrict__ WT,
    const float* __restrict__ bq, const float* __restrict__ bk,
    const float* __restrict__ bv,
    unsigned short* __restrict__ QF, unsigned short* __restrict__ KF,
    unsigned short* __restrict__ VT) {
    __shared__ __align__(16) char smem[2][2][16384];  // [buf][X,W][128 rows x 128B]
    int z = blockIdx.z;
    const unsigned short* Wz = WT + (size_t)z * 1024 * 1024;
    const float* bias = (z == 0) ? bq : ((z == 1) ? bk : bv);
    const int m0 = blockIdx.x * 128, n0 = blockIdx.y * 128;
    const int tid = threadIdx.x, lane = tid & 63, wid = tid >> 6;
    const int wr = wid >> 1, wc = wid & 1;
    const int g = lane >> 4, r16 = lane & 15;
    const int srow = tid >> 3, sch = tid & 7;  // staging: row-in-slab, 16B chunk

    f32x4 acc[4][4] = {};

#define QSTAGE(BUFI, K0)                                                             \
    {                                                                                \
        _Pragma("unroll")                                                            \
        for (int slab = 0; slab < 4; ++slab) {                                       \
            int row = slab * 32 + srow;                                              \
            int sc8 = (sch ^ (row & 7)) * 8;                                         \
            size_t xo = (size_t)(m0 + row) * 1024 + (K0) + sc8;                      \
            size_t wo = (size_t)(n0 + row) * 1024 + (K0) + sc8;                      \
            gload16(XF + xo, &smem[(BUFI)][0][0] + slab * 4096 + tid * 16);          \
            gload16(Wz + wo, &smem[(BUFI)][1][0] + slab * 4096 + tid * 16);          \
        }                                                                            \
    }

    QSTAGE(0, 0);
    for (int ki = 0; ki < 16; ++ki) {
        const int buf = ki & 1;
        if (ki < 15) {
            QSTAGE(buf ^ 1, (ki + 1) * 64);
#ifdef HAVE_GLL
            asm volatile("s_waitcnt vmcnt(8)" ::: "memory");
#endif
        } else {
#ifdef HAVE_GLL
            asm volatile("s_waitcnt vmcnt(0)" ::: "memory");
#endif
        }
        __syncthreads();
        const char* bX = &smem[buf][0][0];
        const char* bW = &smem[buf][1][0];
        const int swz = (r16 & 7) << 4;

        f16x8 af[4][2], bf[4][2];
#pragma unroll
        for (int mi = 0; mi < 4; ++mi) {
            int rb = (wr * 64 + mi * 16 + r16) * 128;
#pragma unroll
            for (int ks = 0; ks < 2; ++ks)
                af[mi][ks] = *(const f16x8*)(bX + rb + (((ks * 4 + g) << 4) ^ swz));
        }
#pragma unroll
        for (int ni = 0; ni < 4; ++ni) {
            int rb = (wc * 64 + ni * 16 + r16) * 128;
#pragma unroll
            for (int ks = 0; ks < 2; ++ks)
                bf[ni][ks] = *(const f16x8*)(bW + rb + (((ks * 4 + g) << 4) ^ swz));
        }
#pragma unroll
        for (int mi = 0; mi < 4; ++mi)
#pragma unroll
            for (int ni = 0; ni < 4; ++ni) {
                acc[mi][ni] = MFMA16(af[mi][0], bf[ni][0], acc[mi][ni]);
                acc[mi][ni] = MFMA16(af[mi][1], bf[ni][1], acc[mi][ni]);
            }
        __syncthreads();
    }

    // epilogue: frag D row = g*4+r (m), col = r16 (n)
#pragma unroll
    for (int mi = 0; mi < 4; ++mi)
#pragma unroll
        for (int ni = 0; ni < 4; ++ni)
#pragma unroll
            for (int r = 0; r < 4; ++r) {
                int m = m0 + wr * 64 + mi * 16 + g * 4 + r;
                int n = n0 + wc * 64 + ni * 16 + r16;
                float val = acc[mi][ni][r] + bias[n];
                if (z == 0) val *= 0.125f;
                int b = m >> 11, s = m & 2047, hh = n >> 6, d = n & 63;
                unsigned short hv = f2h(val);
                if (z == 2) {
                    VT[((size_t)(b * 16 + hh) * 64 + d) * 2048 + s] = hv;
                } else {
                    size_t o = ((size_t)(b * 16 + hh) * 2048 + s) * 64 + d;
                    if (z == 0) QF[o] = hv; else KF[o] = hv;
                }
            }
}

// ---------------------------------------------------------------- attention (flash, 32x32 MFMA, f16)
// grid (16, 32); block 256 = 4 waves, each wave owns 32 q-rows. KVBLK=64.
// K, V staged in LDS (XOR-swizzled via pre-swizzled global addrs), dbuf.
__global__ __launch_bounds__(256, 2) void attn_kernel(
    const unsigned short* __restrict__ QF, const unsigned short* __restrict__ KF,
    const unsigned short* __restrict__ VT, const int* __restrict__ mask,
    float* __restrict__ out) {
    __shared__ __align__(16) char smem[2][2][8192];  // [buf][K,V][64 rows x 128B]
    const int tid = threadIdx.x;
    const int lane = tid & 63, wid = tid >> 6;
    const int hi = lane >> 5, l31 = lane & 31;
    const int bh = blockIdx.y, b = bh >> 4, h = bh & 15;
    const size_t base = (size_t)bh * 2048 * 64;
    const unsigned short* KFh = KF + base;
    const unsigned short* VTh = VT + base;
    const int qrow = blockIdx.x * 128 + wid * 32 + l31;
    const int* mrow = mask + b * 2048;

    // Q fragments (B operand): lane holds q = l31, k-elems = ks*16 + hi*8 .. +7
    f16x8 qf[4];
#pragma unroll
    for (int ks = 0; ks < 4; ++ks)
        qf[ks] = *reinterpret_cast<const f16x8*>(QF + base + (size_t)qrow * 64 + ks * 16 + hi * 8);

    // staging: wave pair -> plane (0:K, 1:V), wave parity -> row half.
    const int lr = (lane >> 3) & 7, c16 = lane & 7;
    const int gce = (c16 ^ lr) << 3;  // element col in source row (8 f16 = 16B)
    const int pl = wid >> 1, half = wid & 1;
    const unsigned short* mys = pl ? VTh : KFh;
    const int rstr = pl ? 2048 : 64;

    f32x16 ctx[2] = {};
    float m_st = -INFINITY, l_st = 0.f;

#define STAGE(BUFI, K0)                                                              \
    {                                                                                \
        char* dst = &smem[(BUFI)][pl][0] + half * 4096;                              \
        size_t koff = pl ? (size_t)(K0) : (size_t)(K0) * 64;                         \
        _Pragma("unroll")                                                            \
        for (int i = 0; i < 4; ++i) {                                                \
            int r = half * 32 + i * 8 + lr;                                          \
            gload16(mys + koff + (size_t)r * rstr + gce, dst + i * 1024 + lane * 16);\
        }                                                                            \
    }

    STAGE(0, 0);
    for (int ch = 0; ch < 32; ++ch) {
        const int k0 = ch * 64;
        const int buf = ch & 1;
        if (ch < 31) {
            STAGE(buf ^ 1, k0 + 64);
#ifdef HAVE_GLL
            asm volatile("s_waitcnt vmcnt(4)" ::: "memory");
#endif
        } else {
#ifdef HAVE_GLL
            asm volatile("s_waitcnt vmcnt(0)" ::: "memory");
#endif
        }
        __syncthreads();
        const char* bK = &smem[buf][0][0];
        const char* bV = &smem[buf][1][0];
        const int swz = (l31 & 7) << 4;

        // ---- QK^T (swapped): A = K rows, B = Q  ->  D[k][q]
        f32x16 sc[2];
#pragma unroll
        for (int kt = 0; kt < 2; ++kt) {
            const char* rK = bK + (kt * 32 + l31) * 128;
            f32x16 a = {};
#pragma unroll
            for (int ks = 0; ks < 4; ++ks)
                a = MFMA32(*(const f16x8*)(rK + ((ks * 32 + hi * 16) ^ swz)), qf[ks], a);
            sc[kt] = a;
        }

        // ---- online softmax (per-lane q; k_local = (r&3)+8*(r>>2)+4*hi+32*kt)
        float p[32];
#pragma unroll
        for (int kt = 0; kt < 2; ++kt)
#pragma unroll
            for (int r = 0; r < 16; ++r) p[kt * 16 + r] = sc[kt][r];
        float mc = p[0];
#pragma unroll
        for (int i = 1; i < 32; ++i) mc = fmaxf(mc, p[i]);
        mc = fmaxf(mc, __shfl_xor(mc, 32));
        float m_new = fmaxf(m_st, mc);
        float fac = __expf(m_st - m_new);
        float psum = 0.f;
#pragma unroll
        for (int kt = 0; kt < 2; ++kt)
#pragma unroll
            for (int G = 0; G < 4; ++G) {
                int4 mk = *reinterpret_cast<const int4*>(mrow + k0 + kt * 32 + 8 * G + 4 * hi);
                int bo = kt * 16 + G * 4;
                float e0 = mk.x ? __expf(p[bo + 0] - m_new) : 0.f;
                float e1 = mk.y ? __expf(p[bo + 1] - m_new) : 0.f;
                float e2 = mk.z ? __expf(p[bo + 2] - m_new) : 0.f;
                float e3 = mk.w ? __expf(p[bo + 3] - m_new) : 0.f;
                p[bo + 0] = e0; p[bo + 1] = e1; p[bo + 2] = e2; p[bo + 3] = e3;
                psum += e0 + e1 + e2 + e3;
            }
        psum += __shfl_xor(psum, 32);
        l_st = l_st * fac + psum;
        m_st = m_new;
        ctx[0] *= fac; ctx[1] *= fac;

        // ---- pack P into PV B-fragments (in-register, halves exchange)
        f16x8 pf[4];
#pragma unroll
        for (int kt = 0; kt < 2; ++kt) {
            int bo = kt * 16;
            unsigned a0 = pk2f(p[bo + 0], p[bo + 1]),   a1 = pk2f(p[bo + 2], p[bo + 3]);
            unsigned b0 = pk2f(p[bo + 4], p[bo + 5]),   b1 = pk2f(p[bo + 6], p[bo + 7]);
            unsigned c0 = pk2f(p[bo + 8], p[bo + 9]),   c1 = pk2f(p[bo + 10], p[bo + 11]);
            unsigned d0 = pk2f(p[bo + 12], p[bo + 13]), d1 = pk2f(p[bo + 14], p[bo + 15]);
            unsigned ta0 = __shfl_xor((int)a0, 32), ta1 = __shfl_xor((int)a1, 32);
            unsigned tb0 = __shfl_xor((int)b0, 32), tb1 = __shfl_xor((int)b1, 32);
            unsigned tc0 = __shfl_xor((int)c0, 32), tc1 = __shfl_xor((int)c1, 32);
            unsigned td0 = __shfl_xor((int)d0, 32), td1 = __shfl_xor((int)d1, 32);
            union { unsigned u[4]; f16x8 v; } f0, f1;
            f0.u[0] = hi ? tb0 : a0; f0.u[1] = hi ? tb1 : a1;
            f0.u[2] = hi ? b0 : ta0; f0.u[3] = hi ? b1 : ta1;
            f1.u[0] = hi ? td0 : c0; f1.u[1] = hi ? td1 : c1;
            f1.u[2] = hi ? d0 : tc0; f1.u[3] = hi ? d1 : tc1;
            pf[kt * 2 + 0] = f0.v; pf[kt * 2 + 1] = f1.v;
        }

        // ---- PV (swapped): A = Vt rows (d), B = P  ->  D[d][q]
#pragma unroll
        for (int dt = 0; dt < 2; ++dt) {
            const char* rV = bV + (dt * 32 + l31) * 128;
            f32x16 a = ctx[dt];
#pragma unroll
            for (int ks = 0; ks < 4; ++ks)
                a = MFMA32(*(const f16x8*)(rV + ((ks * 32 + hi * 16) ^ swz)), pf[ks], a);
            ctx[dt] = a;
        }
        __syncthreads();
    }

    // ---- epilogue: lane q = l31; d = dt*32 + 8*G + 4*hi + j
    float inv_l = 1.0f / l_st;
    size_t ob0 = ((size_t)b * 2048 + qrow) * 1024 + h * 64 + 4 * hi;
#pragma unroll
    for (int dt = 0; dt < 2; ++dt)
#pragma unroll
        for (int G = 0; G < 4; ++G) {
            float4 st;
            st.x = ctx[dt][G * 4 + 0] * inv_l;
            st.y = ctx[dt][G * 4 + 1] * inv_l;
            st.z = ctx[dt][G * 4 + 2] * inv_l;
            st.w = ctx[dt][G * 4 + 3] * inv_l;
            *reinterpret_cast<float4*>(out + ob0 + dt * 32 + 8 * G) = st;
        }
}

// ---------------------------------------------------------------- launch
extern "C" void kernel_launch(void* const* d_in, const int* in_sizes, int n_in,
                              void* d_out, int out_size, void* d_ws, size_t ws_size,
                              hipStream_t stream) {
    const float* X  = (const float*)d_in[0];
    const int* mask = (const int*)d_in[1];
    const float* Wq = (const float*)d_in[2];
    const float* bq = (const float*)d_in[3];
    const float* Wk = (const float*)d_in[4];
    const float* bk = (const float*)d_in[5];
    const float* Wv = (const float*)d_in[6];
    const float* bv = (const float*)d_in[7];
    float* out = (float*)d_out;

    char* ws = (char*)d_ws;
    const size_t SZ_X = (size_t)4096 * 1024 * 2;        // 8 MB f16 X
    const size_t SZ_W = (size_t)1024 * 1024 * 2;        // 2 MB per W plane
    const size_t SZ_Q = (size_t)2 * 16 * 2048 * 64 * 2; // 8 MB per QKV plane
    unsigned short* XF = (unsigned short*)(ws);
    unsigned short* WT = (unsigned short*)(ws + SZ_X);
    unsigned short* QF = (unsigned short*)(ws + SZ_X + 3 * SZ_W);
    unsigned short* KF = (unsigned short*)(ws + SZ_X + 3 * SZ_W + 1 * SZ_Q);
    unsigned short* VT = (unsigned short*)(ws + SZ_X + 3 * SZ_W + 2 * SZ_Q);

    prep_x_kernel<<<4096, 256, 0, stream>>>(X, XF);
    prep_w_kernel<<<dim3(16, 16, 3), 256, 0, stream>>>(Wq, Wk, Wv, WT);
    qkv_gemm_kernel<<<dim3(32, 8, 3), 256, 0, stream>>>(XF, WT, bq, bk, bv, QF, KF, VT);
    attn_kernel<<<dim3(16, 32), 256, 0, stream>>>(QF, KF, VT, mask, out);
}

// Round 6
// 133.341 us; speedup vs baseline: 6.2193x; 1.0649x over previous
//
#include <hip/hip_runtime.h>
#include <math.h>

typedef __attribute__((ext_vector_type(4))) float f32x4;
typedef __attribute__((ext_vector_type(16))) float f32x16;
typedef _Float16 f16x8 __attribute__((ext_vector_type(8)));
typedef __fp16 fp16x2 __attribute__((ext_vector_type(2)));

#define MFMA16(a, b, c) __builtin_amdgcn_mfma_f32_16x16x32_f16((a), (b), (c), 0, 0, 0)
#define MFMA32(a, b, c) __builtin_amdgcn_mfma_f32_32x32x16_f16((a), (b), (c), 0, 0, 0)

__device__ __forceinline__ unsigned short f2h(float f) {
    union { _Float16 h; unsigned short u; } v; v.h = (_Float16)f; return v.u;
}
__device__ __forceinline__ unsigned pk2f(float a, float b) {
    union { fp16x2 h; unsigned u; } v; v.h = __builtin_amdgcn_cvt_pkrtz(a, b); return v.u;
}

#if defined(__has_builtin)
#if __has_builtin(__builtin_amdgcn_global_load_lds)
#define HAVE_GLL 1
#endif
#endif

__device__ __forceinline__ void gload16(const void* g, void* lds) {
#ifdef HAVE_GLL
    __builtin_amdgcn_global_load_lds(
        (const __attribute__((address_space(1))) void*)g,
        (__attribute__((address_space(3))) void*)lds, 16, 0, 0);
#else
    *(f16x8*)lds = *(const f16x8*)g;
#endif
}

// ---------------------------------------------------------------- prep X (f32 -> f16)
__global__ __launch_bounds__(256) void prep_x_kernel(
    const float* __restrict__ X, unsigned short* __restrict__ XF) {
    int i = (blockIdx.x * 256 + threadIdx.x) * 4;
    float4 v = *reinterpret_cast<const float4*>(X + i);
    ushort4 h;
    h.x = f2h(v.x); h.y = f2h(v.y); h.z = f2h(v.z); h.w = f2h(v.w);
    *reinterpret_cast<ushort4*>(XF + i) = h;
}

// ---------------------------------------------------------------- prep mask -> additive log2 bias
// c_k = mask ? -13 (fixed softmax max, log2 units) : -1e9 (exp2 -> exact 0)
__global__ __launch_bounds__(256) void prep_mask_kernel(
    const int* __restrict__ mask, float* __restrict__ cmask) {
    int i = blockIdx.x * 256 + threadIdx.x;
    cmask[i] = mask[i] ? -13.0f : -1e9f;
}

// ---------------------------------------------------------------- prep W (transpose + f16)
__global__ __launch_bounds__(256) void prep_w_kernel(
    const float* __restrict__ Wq, const float* __restrict__ Wk,
    const float* __restrict__ Wv, unsigned short* __restrict__ WT) {
    __shared__ float T[64][65];
    int z = blockIdx.z;
    const float* W = (z == 0) ? Wq : ((z == 1) ? Wk : Wv);
    unsigned short* Wo = WT + (size_t)z * 1024 * 1024;
    int k0 = blockIdx.x * 64, n0 = blockIdx.y * 64;
    int t = threadIdx.x;
    for (int i = 0; i < 4; i++) {
        int fid = t + i * 256;
        int rr = fid >> 4, cc = fid & 15;
        float4 v = *reinterpret_cast<const float4*>(W + (size_t)(k0 + rr) * 1024 + n0 + cc * 4);
        T[rr][cc * 4 + 0] = v.x; T[rr][cc * 4 + 1] = v.y;
        T[rr][cc * 4 + 2] = v.z; T[rr][cc * 4 + 3] = v.w;
    }
    __syncthreads();
    for (int i = 0; i < 4; i++) {
        int e = t + i * 256;
        int n = e >> 4, kq = (e & 15) * 4;
        ushort4 h;
        h.x = f2h(T[kq + 0][n]); h.y = f2h(T[kq + 1][n]);
        h.z = f2h(T[kq + 2][n]); h.w = f2h(T[kq + 3][n]);
        size_t o = (size_t)(n0 + n) * 1024 + k0 + kq;
        *reinterpret_cast<ushort4*>(Wo + o) = h;
    }
}

// ---------------------------------------------------------------- QKV GEMM (f16, m97 structure)
// 128x128 tile, BK=64, 4 waves x (64x64), 2 LDS planes (X, W) XOR-swizzled,
// global_load_lds w16, double-buffered, counted vmcnt(8).
// Q is scaled by 0.125 * log2(e) so attention scores arrive in log2 units.
__global__ __launch_bounds__(256, 2) void qkv_gemm_kernel(
    const unsigned short* __restrict__ XF, const unsigned short* __restrict__ WT,
    const float* __restrict__ bq, const float* __restrict__ bk,
    const float* __restrict__ bv,
    unsigned short* __restrict__ QF, unsigned short* __restrict__ KF,
    unsigned short* __restrict__ VT) {
    __shared__ __align__(16) char smem[2][2][16384];  // [buf][X,W][128 rows x 128B]
    int z = blockIdx.z;
    const unsigned short* Wz = WT + (size_t)z * 1024 * 1024;
    const float* bias = (z == 0) ? bq : ((z == 1) ? bk : bv);
    const int m0 = blockIdx.x * 128, n0 = blockIdx.y * 128;
    const int tid = threadIdx.x, lane = tid & 63, wid = tid >> 6;
    const int wr = wid >> 1, wc = wid & 1;
    const int g = lane >> 4, r16 = lane & 15;
    const int srow = tid >> 3, sch = tid & 7;  // staging: row-in-slab, 16B chunk

    f32x4 acc[4][4] = {};

#define QSTAGE(BUFI, K0)                                                             \
    {                                                                                \
        _Pragma("unroll")                                                            \
        for (int slab = 0; slab < 4; ++slab) {                                       \
            int row = slab * 32 + srow;                                              \
            int sc8 = (sch ^ (row & 7)) * 8;                                         \
            size_t xo = (size_t)(m0 + row) * 1024 + (K0) + sc8;                      \
            size_t wo = (size_t)(n0 + row) * 1024 + (K0) + sc8;                      \
            gload16(XF + xo, &smem[(BUFI)][0][0] + slab * 4096 + tid * 16);          \
            gload16(Wz + wo, &smem[(BUFI)][1][0] + slab * 4096 + tid * 16);          \
        }                                                                            \
    }

    QSTAGE(0, 0);
    for (int ki = 0; ki < 16; ++ki) {
        const int buf = ki & 1;
        if (ki < 15) {
            QSTAGE(buf ^ 1, (ki + 1) * 64);
#ifdef HAVE_GLL
            asm volatile("s_waitcnt vmcnt(8)" ::: "memory");
#endif
        } else {
#ifdef HAVE_GLL
            asm volatile("s_waitcnt vmcnt(0)" ::: "memory");
#endif
        }
        __syncthreads();
        const char* bX = &smem[buf][0][0];
        const char* bW = &smem[buf][1][0];
        const int swz = (r16 & 7) << 4;

        f16x8 af[4][2], bf[4][2];
#pragma unroll
        for (int mi = 0; mi < 4; ++mi) {
            int rb = (wr * 64 + mi * 16 + r16) * 128;
#pragma unroll
            for (int ks = 0; ks < 2; ++ks)
                af[mi][ks] = *(const f16x8*)(bX + rb + (((ks * 4 + g) << 4) ^ swz));
        }
#pragma unroll
        for (int ni = 0; ni < 4; ++ni) {
            int rb = (wc * 64 + ni * 16 + r16) * 128;
#pragma unroll
            for (int ks = 0; ks < 2; ++ks)
                bf[ni][ks] = *(const f16x8*)(bW + rb + (((ks * 4 + g) << 4) ^ swz));
        }
#pragma unroll
        for (int mi = 0; mi < 4; ++mi)
#pragma unroll
            for (int ni = 0; ni < 4; ++ni) {
                acc[mi][ni] = MFMA16(af[mi][0], bf[ni][0], acc[mi][ni]);
                acc[mi][ni] = MFMA16(af[mi][1], bf[ni][1], acc[mi][ni]);
            }
        __syncthreads();
    }

    // epilogue: frag D row = g*4+r (m), col = r16 (n)
#pragma unroll
    for (int mi = 0; mi < 4; ++mi)
#pragma unroll
        for (int ni = 0; ni < 4; ++ni)
#pragma unroll
            for (int r = 0; r < 4; ++r) {
                int m = m0 + wr * 64 + mi * 16 + g * 4 + r;
                int n = n0 + wc * 64 + ni * 16 + r16;
                float val = acc[mi][ni][r] + bias[n];
                if (z == 0) val *= 0.18033688011112042f;  // 0.125 * log2(e)
                int b = m >> 11, s = m & 2047, hh = n >> 6, d = n & 63;
                unsigned short hv = f2h(val);
                if (z == 2) {
                    VT[((size_t)(b * 16 + hh) * 64 + d) * 2048 + s] = hv;
                } else {
                    size_t o = ((size_t)(b * 16 + hh) * 2048 + s) * 64 + d;
                    if (z == 0) QF[o] = hv; else KF[o] = hv;
                }
            }
}

// ---------------------------------------------------------------- attention (flash, 32x32 MFMA, f16)
// grid (16, 32); block 256 = 4 waves, each wave owns 32 q-rows. KVBLK=64.
// Fixed-max softmax: p = exp2(s + c_k), c_k = mask ? -13 : -1e9. No online
// rescale; l accumulated per-lane, reduced once at the end.
__global__ __launch_bounds__(256, 2) void attn_kernel(
    const unsigned short* __restrict__ QF, const unsigned short* __restrict__ KF,
    const unsigned short* __restrict__ VT, const float* __restrict__ cmask,
    float* __restrict__ out) {
    __shared__ __align__(16) char smem[2][2][8192];  // [buf][K,V][64 rows x 128B]
    const int tid = threadIdx.x;
    const int lane = tid & 63, wid = tid >> 6;
    const int hi = lane >> 5, l31 = lane & 31;
    const int bh = blockIdx.y, b = bh >> 4, h = bh & 15;
    const size_t base = (size_t)bh * 2048 * 64;
    const unsigned short* KFh = KF + base;
    const unsigned short* VTh = VT + base;
    const int qrow = blockIdx.x * 128 + wid * 32 + l31;
    const float* crow = cmask + b * 2048;

    // Q fragments (B operand): lane holds q = l31, k-elems = ks*16 + hi*8 .. +7
    f16x8 qf[4];
#pragma unroll
    for (int ks = 0; ks < 4; ++ks)
        qf[ks] = *reinterpret_cast<const f16x8*>(QF + base + (size_t)qrow * 64 + ks * 16 + hi * 8);

    // staging: wave pair -> plane (0:K, 1:V), wave parity -> row half.
    const int lr = (lane >> 3) & 7, c16 = lane & 7;
    const int gce = (c16 ^ lr) << 3;  // element col in source row (8 f16 = 16B)
    const int pl = wid >> 1, half = wid & 1;
    const unsigned short* mys = pl ? VTh : KFh;
    const int rstr = pl ? 2048 : 64;

    f32x16 ctx[2] = {};
    float l_st = 0.f;

#define STAGE(BUFI, K0)                                                              \
    {                                                                                \
        char* dst = &smem[(BUFI)][pl][0] + half * 4096;                              \
        size_t koff = pl ? (size_t)(K0) : (size_t)(K0) * 64;                         \
        _Pragma("unroll")                                                            \
        for (int i = 0; i < 4; ++i) {                                                \
            int r = half * 32 + i * 8 + lr;                                          \
            gload16(mys + koff + (size_t)r * rstr + gce, dst + i * 1024 + lane * 16);\
        }                                                                            \
    }

    STAGE(0, 0);
    for (int ch = 0; ch < 32; ++ch) {
        const int k0 = ch * 64;
        const int buf = ch & 1;
        if (ch < 31) {
            STAGE(buf ^ 1, k0 + 64);
#ifdef HAVE_GLL
            asm volatile("s_waitcnt vmcnt(4)" ::: "memory");
#endif
        } else {
#ifdef HAVE_GLL
            asm volatile("s_waitcnt vmcnt(0)" ::: "memory");
#endif
        }
        __syncthreads();
        const char* bK = &smem[buf][0][0];
        const char* bV = &smem[buf][1][0];
        const int swz = (l31 & 7) << 4;

        // ---- QK^T (swapped): A = K rows, B = Q  ->  D[k][q], log2 units
        f32x16 sc[2];
#pragma unroll
        for (int kt = 0; kt < 2; ++kt) {
            const char* rK = bK + (kt * 32 + l31) * 128;
            f32x16 a = {};
#pragma unroll
            for (int ks = 0; ks < 4; ++ks)
                a = MFMA32(*(const f16x8*)(rK + ((ks * 32 + hi * 16) ^ swz)), qf[ks], a);
            sc[kt] = a;
        }

        // ---- fixed-max softmax: p = exp2(s + c_k); k_local = (r&3)+8*(r>>2)+4*hi
        float p[32];
#pragma unroll
        for (int kt = 0; kt < 2; ++kt)
#pragma unroll
            for (int r = 0; r < 16; ++r) p[kt * 16 + r] = sc[kt][r];
        float psum = 0.f;
#pragma unroll
        for (int kt = 0; kt < 2; ++kt)
#pragma unroll
            for (int G = 0; G < 4; ++G) {
                float4 cv = *reinterpret_cast<const float4*>(crow + k0 + kt * 32 + 8 * G + 4 * hi);
                int bo = kt * 16 + G * 4;
                float e0 = __builtin_amdgcn_exp2f(p[bo + 0] + cv.x);
                float e1 = __builtin_amdgcn_exp2f(p[bo + 1] + cv.y);
                float e2 = __builtin_amdgcn_exp2f(p[bo + 2] + cv.z);
                float e3 = __builtin_amdgcn_exp2f(p[bo + 3] + cv.w);
                p[bo + 0] = e0; p[bo + 1] = e1; p[bo + 2] = e2; p[bo + 3] = e3;
                psum += e0 + e1 + e2 + e3;
            }
        l_st += psum;

        // ---- pack P into PV B-fragments (in-register, halves exchange)
        f16x8 pf[4];
#pragma unroll
        for (int kt = 0; kt < 2; ++kt) {
            int bo = kt * 16;
            unsigned a0 = pk2f(p[bo + 0], p[bo + 1]),   a1 = pk2f(p[bo + 2], p[bo + 3]);
            unsigned b0 = pk2f(p[bo + 4], p[bo + 5]),   b1 = pk2f(p[bo + 6], p[bo + 7]);
            unsigned c0 = pk2f(p[bo + 8], p[bo + 9]),   c1 = pk2f(p[bo + 10], p[bo + 11]);
            unsigned d0 = pk2f(p[bo + 12], p[bo + 13]), d1 = pk2f(p[bo + 14], p[bo + 15]);
            unsigned ta0 = __shfl_xor((int)a0, 32), ta1 = __shfl_xor((int)a1, 32);
            unsigned tb0 = __shfl_xor((int)b0, 32), tb1 = __shfl_xor((int)b1, 32);
            unsigned tc0 = __shfl_xor((int)c0, 32), tc1 = __shfl_xor((int)c1, 32);
            unsigned td0 = __shfl_xor((int)d0, 32), td1 = __shfl_xor((int)d1, 32);
            union { unsigned u[4]; f16x8 v; } f0, f1;
            f0.u[0] = hi ? tb0 : a0; f0.u[1] = hi ? tb1 : a1;
            f0.u[2] = hi ? b0 : ta0; f0.u[3] = hi ? b1 : ta1;
            f1.u[0] = hi ? td0 : c0; f1.u[1] = hi ? td1 : c1;
            f1.u[2] = hi ? d0 : tc0; f1.u[3] = hi ? d1 : tc1;
            pf[kt * 2 + 0] = f0.v; pf[kt * 2 + 1] = f1.v;
        }

        // ---- PV (swapped): A = Vt rows (d), B = P  ->  D[d][q]
#pragma unroll
        for (int dt = 0; dt < 2; ++dt) {
            const char* rV = bV + (dt * 32 + l31) * 128;
            f32x16 a = ctx[dt];
#pragma unroll
            for (int ks = 0; ks < 4; ++ks)
                a = MFMA32(*(const f16x8*)(rV + ((ks * 32 + hi * 16) ^ swz)), pf[ks], a);
            ctx[dt] = a;
        }
        __syncthreads();
    }

    // ---- epilogue: lane q = l31; d = dt*32 + 8*G + 4*hi + j
    float l_full = l_st + __shfl_xor(l_st, 32);
    float inv_l = 1.0f / l_full;
    size_t ob0 = ((size_t)b * 2048 + qrow) * 1024 + h * 64 + 4 * hi;
#pragma unroll
    for (int dt = 0; dt < 2; ++dt)
#pragma unroll
        for (int G = 0; G < 4; ++G) {
            float4 st;
            st.x = ctx[dt][G * 4 + 0] * inv_l;
            st.y = ctx[dt][G * 4 + 1] * inv_l;
            st.z = ctx[dt][G * 4 + 2] * inv_l;
            st.w = ctx[dt][G * 4 + 3] * inv_l;
            *reinterpret_cast<float4*>(out + ob0 + dt * 32 + 8 * G) = st;
        }
}

// ---------------------------------------------------------------- launch
extern "C" void kernel_launch(void* const* d_in, const int* in_sizes, int n_in,
                              void* d_out, int out_size, void* d_ws, size_t ws_size,
                              hipStream_t stream) {
    const float* X  = (const float*)d_in[0];
    const int* mask = (const int*)d_in[1];
    const float* Wq = (const float*)d_in[2];
    const float* bq = (const float*)d_in[3];
    const float* Wk = (const float*)d_in[4];
    const float* bk = (const float*)d_in[5];
    const float* Wv = (const float*)d_in[6];
    const float* bv = (const float*)d_in[7];
    float* out = (float*)d_out;

    char* ws = (char*)d_ws;
    const size_t SZ_X = (size_t)4096 * 1024 * 2;        // 8 MB f16 X
    const size_t SZ_W = (size_t)1024 * 1024 * 2;        // 2 MB per W plane
    const size_t SZ_Q = (size_t)2 * 16 * 2048 * 64 * 2; // 8 MB per QKV plane
    unsigned short* XF = (unsigned short*)(ws);
    unsigned short* WT = (unsigned short*)(ws + SZ_X);
    unsigned short* QF = (unsigned short*)(ws + SZ_X + 3 * SZ_W);
    unsigned short* KF = (unsigned short*)(ws + SZ_X + 3 * SZ_W + 1 * SZ_Q);
    unsigned short* VT = (unsigned short*)(ws + SZ_X + 3 * SZ_W + 2 * SZ_Q);
    float* CM = (float*)(ws + SZ_X + 3 * SZ_W + 3 * SZ_Q);

    prep_x_kernel<<<4096, 256, 0, stream>>>(X, XF);
    prep_mask_kernel<<<16, 256, 0, stream>>>(mask, CM);
    prep_w_kernel<<<dim3(16, 16, 3), 256, 0, stream>>>(Wq, Wk, Wv, WT);
    qkv_gemm_kernel<<<dim3(32, 8, 3), 256, 0, stream>>>(XF, WT, bq, bk, bv, QF, KF, VT);
    attn_kernel<<<dim3(16, 32), 256, 0, stream>>>(QF, KF, VT, CM, out);
}

// Round 7
// 122.871 us; speedup vs baseline: 6.7493x; 1.0852x over previous
//
#include <hip/hip_runtime.h>
#include <math.h>

typedef __attribute__((ext_vector_type(4))) float f32x4;
typedef __attribute__((ext_vector_type(16))) float f32x16;
typedef _Float16 f16x8 __attribute__((ext_vector_type(8)));
typedef __fp16 fp16x2 __attribute__((ext_vector_type(2)));

#define MFMA16(a, b, c) __builtin_amdgcn_mfma_f32_16x16x32_f16((a), (b), (c), 0, 0, 0)
#define MFMA32(a, b, c) __builtin_amdgcn_mfma_f32_32x32x16_f16((a), (b), (c), 0, 0, 0)

__device__ __forceinline__ unsigned short f2h(float f) {
    union { _Float16 h; unsigned short u; } v; v.h = (_Float16)f; return v.u;
}
__device__ __forceinline__ unsigned pk2f(float a, float b) {
    union { fp16x2 h; unsigned u; } v; v.h = __builtin_amdgcn_cvt_pkrtz(a, b); return v.u;
}

#if defined(__has_builtin)
#if __has_builtin(__builtin_amdgcn_global_load_lds)
#define HAVE_GLL 1
#endif
#endif

__device__ __forceinline__ void gload16(const void* g, void* lds) {
#ifdef HAVE_GLL
    __builtin_amdgcn_global_load_lds(
        (const __attribute__((address_space(1))) void*)g,
        (__attribute__((address_space(3))) void*)lds, 16, 0, 0);
#else
    *(f16x8*)lds = *(const f16x8*)g;
#endif
}

// ---------------------------------------------------------------- prep X (f32 -> f16)
__global__ __launch_bounds__(256) void prep_x_kernel(
    const float* __restrict__ X, unsigned short* __restrict__ XF) {
    int i = (blockIdx.x * 256 + threadIdx.x) * 4;
    float4 v = *reinterpret_cast<const float4*>(X + i);
    ushort4 h;
    h.x = f2h(v.x); h.y = f2h(v.y); h.z = f2h(v.z); h.w = f2h(v.w);
    *reinterpret_cast<ushort4*>(XF + i) = h;
}

// ---------------------------------------------------------------- prep mask -> additive log2 bias
__global__ __launch_bounds__(256) void prep_mask_kernel(
    const int* __restrict__ mask, float* __restrict__ cmask) {
    int i = blockIdx.x * 256 + threadIdx.x;
    cmask[i] = mask[i] ? -13.0f : -1e9f;
}

// ---------------------------------------------------------------- prep W (transpose + f16)
__global__ __launch_bounds__(256) void prep_w_kernel(
    const float* __restrict__ Wq, const float* __restrict__ Wk,
    const float* __restrict__ Wv, unsigned short* __restrict__ WT) {
    __shared__ float T[64][65];
    int z = blockIdx.z;
    const float* W = (z == 0) ? Wq : ((z == 1) ? Wk : Wv);
    unsigned short* Wo = WT + (size_t)z * 1024 * 1024;
    int k0 = blockIdx.x * 64, n0 = blockIdx.y * 64;
    int t = threadIdx.x;
    for (int i = 0; i < 4; i++) {
        int fid = t + i * 256;
        int rr = fid >> 4, cc = fid & 15;
        float4 v = *reinterpret_cast<const float4*>(W + (size_t)(k0 + rr) * 1024 + n0 + cc * 4);
        T[rr][cc * 4 + 0] = v.x; T[rr][cc * 4 + 1] = v.y;
        T[rr][cc * 4 + 2] = v.z; T[rr][cc * 4 + 3] = v.w;
    }
    __syncthreads();
    for (int i = 0; i < 4; i++) {
        int e = t + i * 256;
        int n = e >> 4, kq = (e & 15) * 4;
        ushort4 h;
        h.x = f2h(T[kq + 0][n]); h.y = f2h(T[kq + 1][n]);
        h.z = f2h(T[kq + 2][n]); h.w = f2h(T[kq + 3][n]);
        size_t o = (size_t)(n0 + n) * 1024 + k0 + kq;
        *reinterpret_cast<ushort4*>(Wo + o) = h;
    }
}

// ---------------------------------------------------------------- QKV GEMM (f16, single-barrier pipeline)
// 128x128 tile, BK=64, 4 waves x (64x64). One raw s_barrier per K-step:
// vmcnt(0)+lgkm drain -> barrier -> STAGE(next, in flight across compute) -> MFMA.
__global__ __launch_bounds__(256, 2) void qkv_gemm_kernel(
    const unsigned short* __restrict__ XF, const unsigned short* __restrict__ WT,
    const float* __restrict__ bq, const float* __restrict__ bk,
    const float* __restrict__ bv,
    unsigned short* __restrict__ QF, unsigned short* __restrict__ KF,
    unsigned short* __restrict__ VT) {
    __shared__ __align__(16) char smem[2][2][16384];  // [buf][X,W][128 rows x 128B]
    int z = blockIdx.z;
    const unsigned short* Wz = WT + (size_t)z * 1024 * 1024;
    const float* bias = (z == 0) ? bq : ((z == 1) ? bk : bv);
    const int m0 = blockIdx.x * 128, n0 = blockIdx.y * 128;
    const int tid = threadIdx.x, lane = tid & 63, wid = tid >> 6;
    const int wr = wid >> 1, wc = wid & 1;
    const int g = lane >> 4, r16 = lane & 15;
    const int srow = tid >> 3, sch = tid & 7;

    f32x4 acc[4][4] = {};

#define QSTAGE(BUFI, K0)                                                             \
    {                                                                                \
        _Pragma("unroll")                                                            \
        for (int slab = 0; slab < 4; ++slab) {                                       \
            int row = slab * 32 + srow;                                              \
            int sc8 = (sch ^ (row & 7)) * 8;                                         \
            size_t xo = (size_t)(m0 + row) * 1024 + (K0) + sc8;                      \
            size_t wo = (size_t)(n0 + row) * 1024 + (K0) + sc8;                      \
            gload16(XF + xo, &smem[(BUFI)][0][0] + slab * 4096 + tid * 16);          \
            gload16(Wz + wo, &smem[(BUFI)][1][0] + slab * 4096 + tid * 16);          \
        }                                                                            \
    }

    QSTAGE(0, 0);
    for (int ki = 0; ki < 16; ++ki) {
        const int buf = ki & 1;
        asm volatile("s_waitcnt vmcnt(0) lgkmcnt(0)" ::: "memory");
        __builtin_amdgcn_s_barrier();
        if (ki < 15) QSTAGE(buf ^ 1, (ki + 1) * 64);
        const char* bX = &smem[buf][0][0];
        const char* bW = &smem[buf][1][0];
        const int swz = (r16 & 7) << 4;

        f16x8 af[4][2], bf[4][2];
#pragma unroll
        for (int mi = 0; mi < 4; ++mi) {
            int rb = (wr * 64 + mi * 16 + r16) * 128;
#pragma unroll
            for (int ks = 0; ks < 2; ++ks)
                af[mi][ks] = *(const f16x8*)(bX + rb + (((ks * 4 + g) << 4) ^ swz));
        }
#pragma unroll
        for (int ni = 0; ni < 4; ++ni) {
            int rb = (wc * 64 + ni * 16 + r16) * 128;
#pragma unroll
            for (int ks = 0; ks < 2; ++ks)
                bf[ni][ks] = *(const f16x8*)(bW + rb + (((ks * 4 + g) << 4) ^ swz));
        }
        __builtin_amdgcn_s_setprio(1);
#pragma unroll
        for (int mi = 0; mi < 4; ++mi)
#pragma unroll
            for (int ni = 0; ni < 4; ++ni) {
                acc[mi][ni] = MFMA16(af[mi][0], bf[ni][0], acc[mi][ni]);
                acc[mi][ni] = MFMA16(af[mi][1], bf[ni][1], acc[mi][ni]);
            }
        __builtin_amdgcn_s_setprio(0);
    }

    // epilogue: frag D row = g*4+r (m), col = r16 (n)
#pragma unroll
    for (int mi = 0; mi < 4; ++mi)
#pragma unroll
        for (int ni = 0; ni < 4; ++ni)
#pragma unroll
            for (int r = 0; r < 4; ++r) {
                int m = m0 + wr * 64 + mi * 16 + g * 4 + r;
                int n = n0 + wc * 64 + ni * 16 + r16;
                float val = acc[mi][ni][r] + bias[n];
                if (z == 0) val *= 0.18033688011112042f;  // 0.125 * log2(e)
                int b = m >> 11, s = m & 2047, hh = n >> 6, d = n & 63;
                unsigned short hv = f2h(val);
                if (z == 2) {
                    VT[((size_t)(b * 16 + hh) * 64 + d) * 2048 + s] = hv;
                } else {
                    size_t o = ((size_t)(b * 16 + hh) * 2048 + s) * 64 + d;
                    if (z == 0) QF[o] = hv; else KF[o] = hv;
                }
            }
}

// ---------------------------------------------------------------- attention (flash, 32x32 MFMA, f16)
// grid (16, 32); block 256 = 4 waves x 32 q-rows. KVBLK=64, 3-deep LDS buffer,
// ONE barrier per chunk, counted vmcnt(4) keeps 1 chunk in flight across it.
// cmask staged in LDS (broadcast reads, no mid-loop VMEM).
__global__ __launch_bounds__(256, 2) void attn_kernel(
    const unsigned short* __restrict__ QF, const unsigned short* __restrict__ KF,
    const unsigned short* __restrict__ VT, const float* __restrict__ cmask,
    float* __restrict__ out) {
    __shared__ __align__(16) char smem[3][2][8192];  // [buf][K,V][64 rows x 128B]
    __shared__ __align__(16) float cmlds[2048];
    const int tid = threadIdx.x;
    const int lane = tid & 63, wid = tid >> 6;
    const int hi = lane >> 5, l31 = lane & 31;
    const int bh = blockIdx.y, b = bh >> 4, h = bh & 15;
    const size_t base = (size_t)bh * 2048 * 64;
    const unsigned short* KFh = KF + base;
    const unsigned short* VTh = VT + base;
    const int qrow = blockIdx.x * 128 + wid * 32 + l31;
    const float* crow = cmask + b * 2048;

    // Q fragments (B operand): lane holds q = l31, k-elems = ks*16 + hi*8 .. +7
    f16x8 qf[4];
#pragma unroll
    for (int ks = 0; ks < 4; ++ks)
        qf[ks] = *reinterpret_cast<const f16x8*>(QF + base + (size_t)qrow * 64 + ks * 16 + hi * 8);

    // stage cmask row into LDS (8KB, once)
    {
        float4 c0 = *reinterpret_cast<const float4*>(crow + tid * 8);
        float4 c1 = *reinterpret_cast<const float4*>(crow + tid * 8 + 4);
        *reinterpret_cast<float4*>(&cmlds[tid * 8]) = c0;
        *reinterpret_cast<float4*>(&cmlds[tid * 8 + 4]) = c1;
    }

    // staging: wave pair -> plane (0:K, 1:V), wave parity -> row half.
    const int lr = (lane >> 3) & 7, c16 = lane & 7;
    const int gce = (c16 ^ lr) << 3;  // element col in source row (8 f16 = 16B)
    const int pl = wid >> 1, half = wid & 1;
    const unsigned short* mys = pl ? VTh : KFh;
    const int rstr = pl ? 2048 : 64;

    f32x16 ctx[2] = {};
    float l_st = 0.f;

#define STAGE(BUFI, K0)                                                              \
    {                                                                                \
        char* dst = &smem[(BUFI)][pl][0] + half * 4096;                              \
        size_t koff = pl ? (size_t)(K0) : (size_t)(K0) * 64;                         \
        _Pragma("unroll")                                                            \
        for (int i = 0; i < 4; ++i) {                                                \
            int r = half * 32 + i * 8 + lr;                                          \
            gload16(mys + koff + (size_t)r * rstr + gce, dst + i * 1024 + lane * 16);\
        }                                                                            \
    }

    STAGE(0, 0);
    STAGE(1, 64);
    int bufc = 0, bufs = 2;
    for (int ch = 0; ch < 32; ++ch) {
        const int k0 = ch * 64;
        if (ch < 31) {
            asm volatile("s_waitcnt vmcnt(4) lgkmcnt(0)" ::: "memory");
        } else {
            asm volatile("s_waitcnt vmcnt(0) lgkmcnt(0)" ::: "memory");
        }
        __builtin_amdgcn_s_barrier();
        if (ch < 30) STAGE(bufs, k0 + 128);

        const char* bK = &smem[bufc][0][0];
        const char* bV = &smem[bufc][1][0];
        const int swz = (l31 & 7) << 4;

        // ---- QK^T (swapped): A = K rows, B = Q  ->  D[k][q], log2 units
        f32x16 sc[2];
        __builtin_amdgcn_s_setprio(1);
#pragma unroll
        for (int kt = 0; kt < 2; ++kt) {
            const char* rK = bK + (kt * 32 + l31) * 128;
            f32x16 a = {};
#pragma unroll
            for (int ks = 0; ks < 4; ++ks)
                a = MFMA32(*(const f16x8*)(rK + ((ks * 32 + hi * 16) ^ swz)), qf[ks], a);
            sc[kt] = a;
        }
        __builtin_amdgcn_s_setprio(0);

        // ---- fixed-max softmax: p = exp2(s + c_k); k_local = (r&3)+8*(r>>2)+4*hi
        float p[32];
#pragma unroll
        for (int kt = 0; kt < 2; ++kt)
#pragma unroll
            for (int r = 0; r < 16; ++r) p[kt * 16 + r] = sc[kt][r];
        float psum = 0.f;
#pragma unroll
        for (int kt = 0; kt < 2; ++kt)
#pragma unroll
            for (int G = 0; G < 4; ++G) {
                float4 cv = *reinterpret_cast<const float4*>(&cmlds[k0 + kt * 32 + 8 * G + 4 * hi]);
                int bo = kt * 16 + G * 4;
                float e0 = __builtin_amdgcn_exp2f(p[bo + 0] + cv.x);
                float e1 = __builtin_amdgcn_exp2f(p[bo + 1] + cv.y);
                float e2 = __builtin_amdgcn_exp2f(p[bo + 2] + cv.z);
                float e3 = __builtin_amdgcn_exp2f(p[bo + 3] + cv.w);
                p[bo + 0] = e0; p[bo + 1] = e1; p[bo + 2] = e2; p[bo + 3] = e3;
                psum += e0 + e1 + e2 + e3;
            }
        l_st += psum;

        // ---- pack P into PV B-fragments (in-register, halves exchange)
        f16x8 pf[4];
#pragma unroll
        for (int kt = 0; kt < 2; ++kt) {
            int bo = kt * 16;
            unsigned a0 = pk2f(p[bo + 0], p[bo + 1]),   a1 = pk2f(p[bo + 2], p[bo + 3]);
            unsigned b0 = pk2f(p[bo + 4], p[bo + 5]),   b1 = pk2f(p[bo + 6], p[bo + 7]);
            unsigned c0 = pk2f(p[bo + 8], p[bo + 9]),   c1 = pk2f(p[bo + 10], p[bo + 11]);
            unsigned d0 = pk2f(p[bo + 12], p[bo + 13]), d1 = pk2f(p[bo + 14], p[bo + 15]);
            unsigned ta0 = __shfl_xor((int)a0, 32), ta1 = __shfl_xor((int)a1, 32);
            unsigned tb0 = __shfl_xor((int)b0, 32), tb1 = __shfl_xor((int)b1, 32);
            unsigned tc0 = __shfl_xor((int)c0, 32), tc1 = __shfl_xor((int)c1, 32);
            unsigned td0 = __shfl_xor((int)d0, 32), td1 = __shfl_xor((int)d1, 32);
            union { unsigned u[4]; f16x8 v; } f0, f1;
            f0.u[0] = hi ? tb0 : a0; f0.u[1] = hi ? tb1 : a1;
            f0.u[2] = hi ? b0 : ta0; f0.u[3] = hi ? b1 : ta1;
            f1.u[0] = hi ? td0 : c0; f1.u[1] = hi ? td1 : c1;
            f1.u[2] = hi ? d0 : tc0; f1.u[3] = hi ? d1 : tc1;
            pf[kt * 2 + 0] = f0.v; pf[kt * 2 + 1] = f1.v;
        }

        // ---- PV (swapped): A = Vt rows (d), B = P  ->  D[d][q]
        __builtin_amdgcn_s_setprio(1);
#pragma unroll
        for (int dt = 0; dt < 2; ++dt) {
            const char* rV = bV + (dt * 32 + l31) * 128;
            f32x16 a = ctx[dt];
#pragma unroll
            for (int ks = 0; ks < 4; ++ks)
                a = MFMA32(*(const f16x8*)(rV + ((ks * 32 + hi * 16) ^ swz)), pf[ks], a);
            ctx[dt] = a;
        }
        __builtin_amdgcn_s_setprio(0);

        bufc = (bufc == 2) ? 0 : bufc + 1;
        bufs = (bufs == 2) ? 0 : bufs + 1;
    }

    // ---- epilogue: lane q = l31; d = dt*32 + 8*G + 4*hi + j
    float l_full = l_st + __shfl_xor(l_st, 32);
    float inv_l = 1.0f / l_full;
    size_t ob0 = ((size_t)b * 2048 + qrow) * 1024 + h * 64 + 4 * hi;
#pragma unroll
    for (int dt = 0; dt < 2; ++dt)
#pragma unroll
        for (int G = 0; G < 4; ++G) {
            float4 st;
            st.x = ctx[dt][G * 4 + 0] * inv_l;
            st.y = ctx[dt][G * 4 + 1] * inv_l;
            st.z = ctx[dt][G * 4 + 2] * inv_l;
            st.w = ctx[dt][G * 4 + 3] * inv_l;
            *reinterpret_cast<float4*>(out + ob0 + dt * 32 + 8 * G) = st;
        }
}

// ---------------------------------------------------------------- launch
extern "C" void kernel_launch(void* const* d_in, const int* in_sizes, int n_in,
                              void* d_out, int out_size, void* d_ws, size_t ws_size,
                              hipStream_t stream) {
    const float* X  = (const float*)d_in[0];
    const int* mask = (const int*)d_in[1];
    const float* Wq = (const float*)d_in[2];
    const float* bq = (const float*)d_in[3];
    const float* Wk = (const float*)d_in[4];
    const float* bk = (const float*)d_in[5];
    const float* Wv = (const float*)d_in[6];
    const float* bv = (const float*)d_in[7];
    float* out = (float*)d_out;

    char* ws = (char*)d_ws;
    const size_t SZ_X = (size_t)4096 * 1024 * 2;        // 8 MB f16 X
    const size_t SZ_W = (size_t)1024 * 1024 * 2;        // 2 MB per W plane
    const size_t SZ_Q = (size_t)2 * 16 * 2048 * 64 * 2; // 8 MB per QKV plane
    unsigned short* XF = (unsigned short*)(ws);
    unsigned short* WT = (unsigned short*)(ws + SZ_X);
    unsigned short* QF = (unsigned short*)(ws + SZ_X + 3 * SZ_W);
    unsigned short* KF = (unsigned short*)(ws + SZ_X + 3 * SZ_W + 1 * SZ_Q);
    unsigned short* VT = (unsigned short*)(ws + SZ_X + 3 * SZ_W + 2 * SZ_Q);
    float* CM = (float*)(ws + SZ_X + 3 * SZ_W + 3 * SZ_Q);

    prep_x_kernel<<<4096, 256, 0, stream>>>(X, XF);
    prep_mask_kernel<<<16, 256, 0, stream>>>(mask, CM);
    prep_w_kernel<<<dim3(16, 16, 3), 256, 0, stream>>>(Wq, Wk, Wv, WT);
    qkv_gemm_kernel<<<dim3(32, 8, 3), 256, 0, stream>>>(XF, WT, bq, bk, bv, QF, KF, VT);
    attn_kernel<<<dim3(16, 32), 256, 0, stream>>>(QF, KF, VT, CM, out);
}

// Round 8
// 114.927 us; speedup vs baseline: 7.2158x; 1.0691x over previous
//
#include <hip/hip_runtime.h>
#include <math.h>

typedef __attribute__((ext_vector_type(4))) float f32x4;
typedef __attribute__((ext_vector_type(16))) float f32x16;
typedef _Float16 f16x8 __attribute__((ext_vector_type(8)));
typedef __fp16 fp16x2 __attribute__((ext_vector_type(2)));

#define MFMA16(a, b, c) __builtin_amdgcn_mfma_f32_16x16x32_f16((a), (b), (c), 0, 0, 0)
#define MFMA32(a, b, c) __builtin_amdgcn_mfma_f32_32x32x16_f16((a), (b), (c), 0, 0, 0)

__device__ __forceinline__ unsigned short f2h(float f) {
    union { _Float16 h; unsigned short u; } v; v.h = (_Float16)f; return v.u;
}
__device__ __forceinline__ unsigned pk2f(float a, float b) {
    union { fp16x2 h; unsigned u; } v; v.h = __builtin_amdgcn_cvt_pkrtz(a, b); return v.u;
}

#if defined(__has_builtin)
#if __has_builtin(__builtin_amdgcn_global_load_lds)
#define HAVE_GLL 1
#endif
#endif

__device__ __forceinline__ void gload16(const void* g, void* lds) {
#ifdef HAVE_GLL
    __builtin_amdgcn_global_load_lds(
        (const __attribute__((address_space(1))) void*)g,
        (__attribute__((address_space(3))) void*)lds, 16, 0, 0);
#else
    *(f16x8*)lds = *(const f16x8*)g;
#endif
}

// ---------------------------------------------------------------- prep X (f32 -> f16)
__global__ __launch_bounds__(256) void prep_x_kernel(
    const float* __restrict__ X, unsigned short* __restrict__ XF) {
    int i = (blockIdx.x * 256 + threadIdx.x) * 4;
    float4 v = *reinterpret_cast<const float4*>(X + i);
    ushort4 h;
    h.x = f2h(v.x); h.y = f2h(v.y); h.z = f2h(v.z); h.w = f2h(v.w);
    *reinterpret_cast<ushort4*>(XF + i) = h;
}

// ---------------------------------------------------------------- prep W (transpose + f16)
__global__ __launch_bounds__(256) void prep_w_kernel(
    const float* __restrict__ Wq, const float* __restrict__ Wk,
    const float* __restrict__ Wv, unsigned short* __restrict__ WT) {
    __shared__ float T[64][65];
    int z = blockIdx.z;
    const float* W = (z == 0) ? Wq : ((z == 1) ? Wk : Wv);
    unsigned short* Wo = WT + (size_t)z * 1024 * 1024;
    int k0 = blockIdx.x * 64, n0 = blockIdx.y * 64;
    int t = threadIdx.x;
    for (int i = 0; i < 4; i++) {
        int fid = t + i * 256;
        int rr = fid >> 4, cc = fid & 15;
        float4 v = *reinterpret_cast<const float4*>(W + (size_t)(k0 + rr) * 1024 + n0 + cc * 4);
        T[rr][cc * 4 + 0] = v.x; T[rr][cc * 4 + 1] = v.y;
        T[rr][cc * 4 + 2] = v.z; T[rr][cc * 4 + 3] = v.w;
    }
    __syncthreads();
    for (int i = 0; i < 4; i++) {
        int e = t + i * 256;
        int n = e >> 4, kq = (e & 15) * 4;
        ushort4 h;
        h.x = f2h(T[kq + 0][n]); h.y = f2h(T[kq + 1][n]);
        h.z = f2h(T[kq + 2][n]); h.w = f2h(T[kq + 3][n]);
        size_t o = (size_t)(n0 + n) * 1024 + k0 + kq;
        *reinterpret_cast<ushort4*>(Wo + o) = h;
    }
}

// ---------------------------------------------------------------- QKV GEMM (f16, counted-vmcnt pipeline)
// 128x128 tile, BK=32, 3-deep LDS (48KB -> 3 blocks/CU), 4 waves x (64x64).
// Per step: vmcnt(4) -> barrier -> stage(ki+2) -> 8 ds_read + 16 MFMA.
__global__ __launch_bounds__(256, 3) void qkv_gemm_kernel(
    const unsigned short* __restrict__ XF, const unsigned short* __restrict__ WT,
    const float* __restrict__ bq, const float* __restrict__ bk,
    const float* __restrict__ bv,
    unsigned short* __restrict__ QF, unsigned short* __restrict__ KF,
    unsigned short* __restrict__ VT) {
    __shared__ __align__(16) char smem[3][2][8192];  // [buf][X,W][128 rows x 64B]
    int z = blockIdx.z;
    const unsigned short* Wz = WT + (size_t)z * 1024 * 1024;
    const float* bias = (z == 0) ? bq : ((z == 1) ? bk : bv);
    const int m0 = blockIdx.x * 128, n0 = blockIdx.y * 128;
    const int tid = threadIdx.x, lane = tid & 63, wid = tid >> 6;
    const int wr = wid >> 1, wc = wid & 1;
    const int g = lane >> 4, r16 = lane & 15;

    f32x4 acc[4][4] = {};

#define QSTAGE(BUFI, K0)                                                             \
    {                                                                                \
        _Pragma("unroll")                                                            \
        for (int p = 0; p < 2; ++p) {                                                \
            int row = p * 64 + (tid >> 2);                                           \
            int ec = ((tid & 3) ^ (row & 3)) * 8;                                    \
            size_t xo = (size_t)(m0 + row) * 1024 + (K0) + ec;                       \
            size_t wo = (size_t)(n0 + row) * 1024 + (K0) + ec;                       \
            gload16(XF + xo, &smem[(BUFI)][0][0] + p * 4096 + tid * 16);             \
            gload16(Wz + wo, &smem[(BUFI)][1][0] + p * 4096 + tid * 16);             \
        }                                                                            \
    }

    QSTAGE(0, 0);
    QSTAGE(1, 32);
    int bufc = 0, bufs = 2;
    for (int ki = 0; ki < 32; ++ki) {
        if (ki < 31) {
            asm volatile("s_waitcnt vmcnt(4)" ::: "memory");
        } else {
            asm volatile("s_waitcnt vmcnt(0)" ::: "memory");
        }
        __builtin_amdgcn_s_barrier();
        if (ki < 30) QSTAGE(bufs, (ki + 2) * 32);
        const char* bX = &smem[bufc][0][0];
        const char* bW = &smem[bufc][1][0];
        const int sx = (r16 & 3) << 4;

        f16x8 af[4], bf[4];
#pragma unroll
        for (int mi = 0; mi < 4; ++mi)
            af[mi] = *(const f16x8*)(bX + (wr * 64 + mi * 16 + r16) * 64 + ((g << 4) ^ sx));
#pragma unroll
        for (int ni = 0; ni < 4; ++ni)
            bf[ni] = *(const f16x8*)(bW + (wc * 64 + ni * 16 + r16) * 64 + ((g << 4) ^ sx));
        __builtin_amdgcn_s_setprio(1);
#pragma unroll
        for (int mi = 0; mi < 4; ++mi)
#pragma unroll
            for (int ni = 0; ni < 4; ++ni)
                acc[mi][ni] = MFMA16(af[mi], bf[ni], acc[mi][ni]);
        __builtin_amdgcn_s_setprio(0);
        bufc = (bufc == 2) ? 0 : bufc + 1;
        bufs = (bufs == 2) ? 0 : bufs + 1;
    }

    // epilogue: frag D row = g*4+r (m), col = r16 (n)
#pragma unroll
    for (int mi = 0; mi < 4; ++mi)
#pragma unroll
        for (int ni = 0; ni < 4; ++ni)
#pragma unroll
            for (int r = 0; r < 4; ++r) {
                int m = m0 + wr * 64 + mi * 16 + g * 4 + r;
                int n = n0 + wc * 64 + ni * 16 + r16;
                float val = acc[mi][ni][r] + bias[n];
                if (z == 0) val *= 0.18033688011112042f;  // 0.125 * log2(e)
                int b = m >> 11, s = m & 2047, hh = n >> 6, d = n & 63;
                unsigned short hv = f2h(val);
                if (z == 2) {
                    VT[((size_t)(b * 16 + hh) * 64 + d) * 2048 + s] = hv;
                } else {
                    size_t o = ((size_t)(b * 16 + hh) * 2048 + s) * 64 + d;
                    if (z == 0) QF[o] = hv; else KF[o] = hv;
                }
            }
}

// ---------------------------------------------------------------- attention (flash, 32x32 MFMA, f16)
// grid (16, 32); 4 waves x 32 q-rows. KVBLK=64, 4-deep LDS, one barrier/chunk,
// vmcnt(4)->barrier ledger, QK^T(ch+1) issued before softmax/PV(ch) (2 score sets).
__global__ __launch_bounds__(256, 2) void attn_kernel(
    const unsigned short* __restrict__ QF, const unsigned short* __restrict__ KF,
    const unsigned short* __restrict__ VT, const int* __restrict__ mask,
    float* __restrict__ out) {
    __shared__ __align__(16) char smem[4][2][8192];  // [buf][K,V][64 rows x 128B]
    __shared__ __align__(16) float cmlds[2048];
    const int tid = threadIdx.x;
    const int lane = tid & 63, wid = tid >> 6;
    const int hi = lane >> 5, l31 = lane & 31;
    const int bh = blockIdx.y, b = bh >> 4, h = bh & 15;
    const size_t base = (size_t)bh * 2048 * 64;
    const unsigned short* KFh = KF + base;
    const unsigned short* VTh = VT + base;
    const int qrow = blockIdx.x * 128 + wid * 32 + l31;
    const int swz = (l31 & 7) << 4;

    // Q fragments (B operand): lane holds q = l31, k-elems = ks*16 + hi*8 .. +7
    f16x8 qf[4];
#pragma unroll
    for (int ks = 0; ks < 4; ++ks)
        qf[ks] = *reinterpret_cast<const f16x8*>(QF + base + (size_t)qrow * 64 + ks * 16 + hi * 8);

    // staging: wave pair -> plane (0:K, 1:V), wave parity -> row half.
    const int lr = (lane >> 3) & 7, c16 = lane & 7;
    const int gce = (c16 ^ lr) << 3;
    const int pl = wid >> 1, half = wid & 1;
    const unsigned short* mys = pl ? VTh : KFh;
    const int rstr = pl ? 2048 : 64;

    f32x16 ctx[2] = {};
    float l_st = 0.f;

#define STAGE(BUFI, K0)                                                              \
    {                                                                                \
        char* dst = &smem[(BUFI)][pl][0] + half * 4096;                              \
        size_t koff = pl ? (size_t)(K0) : (size_t)(K0) * 64;                         \
        _Pragma("unroll")                                                            \
        for (int i = 0; i < 4; ++i) {                                                \
            int r = half * 32 + i * 8 + lr;                                          \
            gload16(mys + koff + (size_t)r * rstr + gce, dst + i * 1024 + lane * 16);\
        }                                                                            \
    }

#define QKT(CH, SC)                                                                  \
    {                                                                                \
        const char* bK = &smem[(CH) & 3][0][0];                                      \
        __builtin_amdgcn_s_setprio(1);                                               \
        _Pragma("unroll")                                                            \
        for (int kt = 0; kt < 2; ++kt) {                                             \
            const char* rK = bK + (kt * 32 + l31) * 128;                             \
            f32x16 a = {};                                                           \
            _Pragma("unroll")                                                        \
            for (int ks = 0; ks < 4; ++ks)                                           \
                a = MFMA32(*(const f16x8*)(rK + ((ks * 32 + hi * 16) ^ swz)),        \
                           qf[ks], a);                                               \
            SC[kt] = a;                                                              \
        }                                                                            \
        __builtin_amdgcn_s_setprio(0);                                               \
    }

#define SMPV(CH, SC)                                                                 \
    {                                                                                \
        const int k0s = (CH) * 64;                                                   \
        const char* bV = &smem[(CH) & 3][1][0];                                      \
        float p[32];                                                                 \
        _Pragma("unroll")                                                            \
        for (int kt = 0; kt < 2; ++kt)                                               \
            _Pragma("unroll")                                                        \
            for (int r = 0; r < 16; ++r) p[kt * 16 + r] = SC[kt][r];                 \
        float psum = 0.f;                                                            \
        _Pragma("unroll")                                                            \
        for (int kt = 0; kt < 2; ++kt)                                               \
            _Pragma("unroll")                                                        \
            for (int G = 0; G < 4; ++G) {                                            \
                float4 cv = *reinterpret_cast<const float4*>(                        \
                    &cmlds[k0s + kt * 32 + 8 * G + 4 * hi]);                         \
                int bo = kt * 16 + G * 4;                                            \
                float e0 = __builtin_amdgcn_exp2f(p[bo + 0] + cv.x);                 \
                float e1 = __builtin_amdgcn_exp2f(p[bo + 1] + cv.y);                 \
                float e2 = __builtin_amdgcn_exp2f(p[bo + 2] + cv.z);                 \
                float e3 = __builtin_amdgcn_exp2f(p[bo + 3] + cv.w);                 \
                p[bo + 0] = e0; p[bo + 1] = e1; p[bo + 2] = e2; p[bo + 3] = e3;      \
                psum += e0 + e1 + e2 + e3;                                           \
            }                                                                        \
        l_st += psum;                                                                \
        f16x8 pf[4];                                                                 \
        _Pragma("unroll")                                                            \
        for (int kt = 0; kt < 2; ++kt) {                                             \
            int bo = kt * 16;                                                        \
            unsigned a0 = pk2f(p[bo + 0], p[bo + 1]),   a1 = pk2f(p[bo + 2], p[bo + 3]);   \
            unsigned b0 = pk2f(p[bo + 4], p[bo + 5]),   b1 = pk2f(p[bo + 6], p[bo + 7]);   \
            unsigned c0 = pk2f(p[bo + 8], p[bo + 9]),   c1 = pk2f(p[bo + 10], p[bo + 11]); \
            unsigned d0 = pk2f(p[bo + 12], p[bo + 13]), d1 = pk2f(p[bo + 14], p[bo + 15]); \
            unsigned ta0 = __shfl_xor((int)a0, 32), ta1 = __shfl_xor((int)a1, 32);   \
            unsigned tb0 = __shfl_xor((int)b0, 32), tb1 = __shfl_xor((int)b1, 32);   \
            unsigned tc0 = __shfl_xor((int)c0, 32), tc1 = __shfl_xor((int)c1, 32);   \
            unsigned td0 = __shfl_xor((int)d0, 32), td1 = __shfl_xor((int)d1, 32);   \
            union { unsigned u[4]; f16x8 v; } f0, f1;                                \
            f0.u[0] = hi ? tb0 : a0; f0.u[1] = hi ? tb1 : a1;                        \
            f0.u[2] = hi ? b0 : ta0; f0.u[3] = hi ? b1 : ta1;                        \
            f1.u[0] = hi ? td0 : c0; f1.u[1] = hi ? td1 : c1;                        \
            f1.u[2] = hi ? d0 : tc0; f1.u[3] = hi ? d1 : tc1;                        \
            pf[kt * 2 + 0] = f0.v; pf[kt * 2 + 1] = f1.v;                            \
        }                                                                            \
        __builtin_amdgcn_s_setprio(1);                                               \
        _Pragma("unroll")                                                            \
        for (int dt = 0; dt < 2; ++dt) {                                             \
            const char* rV = bV + (dt * 32 + l31) * 128;                             \
            f32x16 a = ctx[dt];                                                      \
            _Pragma("unroll")                                                        \
            for (int ks = 0; ks < 4; ++ks)                                           \
                a = MFMA32(*(const f16x8*)(rV + ((ks * 32 + hi * 16) ^ swz)),        \
                           pf[ks], a);                                               \
            ctx[dt] = a;                                                             \
        }                                                                            \
        __builtin_amdgcn_s_setprio(0);                                               \
    }

#define WAIT4 asm volatile("s_waitcnt vmcnt(4)" ::: "memory")
#define WAIT0 asm volatile("s_waitcnt vmcnt(0)" ::: "memory")
#define BAR __builtin_amdgcn_s_barrier()

    STAGE(0, 0);
    STAGE(1, 64);
    STAGE(2, 128);
    // cmask -> LDS (c = mask ? -13 : -1e9), overlaps staging flight
    {
        const int* mrow = mask + b * 2048;
        int4 m0v = *reinterpret_cast<const int4*>(mrow + tid * 8);
        int4 m1v = *reinterpret_cast<const int4*>(mrow + tid * 8 + 4);
        float4 c0, c1;
        c0.x = m0v.x ? -13.f : -1e9f; c0.y = m0v.y ? -13.f : -1e9f;
        c0.z = m0v.z ? -13.f : -1e9f; c0.w = m0v.w ? -13.f : -1e9f;
        c1.x = m1v.x ? -13.f : -1e9f; c1.y = m1v.y ? -13.f : -1e9f;
        c1.z = m1v.z ? -13.f : -1e9f; c1.w = m1v.w ? -13.f : -1e9f;
        *reinterpret_cast<float4*>(&cmlds[tid * 8]) = c0;
        *reinterpret_cast<float4*>(&cmlds[tid * 8 + 4]) = c1;
    }
    asm volatile("s_waitcnt vmcnt(8)" ::: "memory");
    BAR;

    f32x16 scA[2], scB[2];
    QKT(0, scA);
    for (int ch = 0; ch < 28; ch += 2) {
        WAIT4; BAR;
        STAGE((ch + 3) & 3, (ch + 3) * 64);
        QKT(ch + 1, scB);
        SMPV(ch, scA);
        WAIT4; BAR;
        STAGE((ch + 4) & 3, (ch + 4) * 64);
        QKT(ch + 2, scA);
        SMPV(ch + 1, scB);
    }
    // ch = 28
    WAIT4; BAR;
    STAGE(3, 31 * 64);
    QKT(29, scB);
    SMPV(28, scA);
    // ch = 29
    WAIT4; BAR;
    QKT(30, scA);
    SMPV(29, scB);
    // ch = 30
    WAIT0; BAR;
    QKT(31, scB);
    SMPV(30, scA);
    // ch = 31
    SMPV(31, scB);

    // ---- epilogue: lane q = l31; d = dt*32 + 8*G + 4*hi + j
    float l_full = l_st + __shfl_xor(l_st, 32);
    float inv_l = 1.0f / l_full;
    size_t ob0 = ((size_t)b * 2048 + qrow) * 1024 + h * 64 + 4 * hi;
#pragma unroll
    for (int dt = 0; dt < 2; ++dt)
#pragma unroll
        for (int G = 0; G < 4; ++G) {
            float4 st;
            st.x = ctx[dt][G * 4 + 0] * inv_l;
            st.y = ctx[dt][G * 4 + 1] * inv_l;
            st.z = ctx[dt][G * 4 + 2] * inv_l;
            st.w = ctx[dt][G * 4 + 3] * inv_l;
            *reinterpret_cast<float4*>(out + ob0 + dt * 32 + 8 * G) = st;
        }
}

// ---------------------------------------------------------------- launch
extern "C" void kernel_launch(void* const* d_in, const int* in_sizes, int n_in,
                              void* d_out, int out_size, void* d_ws, size_t ws_size,
                              hipStream_t stream) {
    const float* X  = (const float*)d_in[0];
    const int* mask = (const int*)d_in[1];
    const float* Wq = (const float*)d_in[2];
    const float* bq = (const float*)d_in[3];
    const float* Wk = (const float*)d_in[4];
    const float* bk = (const float*)d_in[5];
    const float* Wv = (const float*)d_in[6];
    const float* bv = (const float*)d_in[7];
    float* out = (float*)d_out;

    char* ws = (char*)d_ws;
    const size_t SZ_X = (size_t)4096 * 1024 * 2;        // 8 MB f16 X
    const size_t SZ_W = (size_t)1024 * 1024 * 2;        // 2 MB per W plane
    const size_t SZ_Q = (size_t)2 * 16 * 2048 * 64 * 2; // 8 MB per QKV plane
    unsigned short* XF = (unsigned short*)(ws);
    unsigned short* WT = (unsigned short*)(ws + SZ_X);
    unsigned short* QF = (unsigned short*)(ws + SZ_X + 3 * SZ_W);
    unsigned short* KF = (unsigned short*)(ws + SZ_X + 3 * SZ_W + 1 * SZ_Q);
    unsigned short* VT = (unsigned short*)(ws + SZ_X + 3 * SZ_W + 2 * SZ_Q);

    prep_x_kernel<<<4096, 256, 0, stream>>>(X, XF);
    prep_w_kernel<<<dim3(16, 16, 3), 256, 0, stream>>>(Wq, Wk, Wv, WT);
    qkv_gemm_kernel<<<dim3(32, 8, 3), 256, 0, stream>>>(XF, WT, bq, bk, bv, QF, KF, VT);
    attn_kernel<<<dim3(16, 32), 256, 0, stream>>>(QF, KF, VT, mask, out);
}